// Round 5
// baseline (6053.843 us; speedup 1.0000x reference)
//
#include <hip/hip_runtime.h>
#include <math.h>

// ---------------- problem constants ----------------
#define BB 2
#define HH 192
#define WW 192
#define NN 36864
#define CC 192
#define NHEAD 6
#define HD 32
#define MM 64
#define RC 10
#define GS 256
#define NG 144
#define HID 384
#define BN 73728

typedef unsigned short u16;

__device__ __forceinline__ float b2f(u16 u) { return __uint_as_float(((unsigned)u) << 16); }
__device__ __forceinline__ u16 f2b(float f) {
  unsigned v = __float_as_uint(f);
  return (u16)((v + 0x7fffu + ((v >> 16) & 1u)) >> 16);
}
__device__ __forceinline__ void up8(uint4 u, float* f) {
  f[0] = __uint_as_float(u.x << 16); f[1] = __uint_as_float(u.x & 0xffff0000u);
  f[2] = __uint_as_float(u.y << 16); f[3] = __uint_as_float(u.y & 0xffff0000u);
  f[4] = __uint_as_float(u.z << 16); f[5] = __uint_as_float(u.z & 0xffff0000u);
  f[6] = __uint_as_float(u.w << 16); f[7] = __uint_as_float(u.w & 0xffff0000u);
}
__device__ __forceinline__ float gelu_f(float v) {
  return 0.5f * v * (1.f + erff(v * 0.70710678118654752f));
}

// ---------------- zero scratch ----------------
__global__ void zero_kernel(int* __restrict__ p, int n) {
  int i = blockIdx.x * 256 + threadIdx.x;
  if (i < n) p[i] = 0;
}

// ---------------- LN1 fused with ATD q projection (fp32 path) ----------------
__global__ __launch_bounds__(256) void ln1_kernel(const float* __restrict__ x,
                                                  const float* __restrict__ g,
                                                  const float* __restrict__ be,
                                                  const float* __restrict__ wq,
                                                  const float* __restrict__ wqb,
                                                  u16* __restrict__ xnb,
                                                  float* __restrict__ qn) {
  int row = blockIdx.x * 4 + (threadIdx.x >> 6);
  int lane = threadIdx.x & 63;
  const float* p = x + (size_t)row * CC;
  float v0 = p[lane], v1 = p[lane + 64], v2 = p[lane + 128];
  float s = v0 + v1 + v2;
#pragma unroll
  for (int o = 32; o > 0; o >>= 1) s += __shfl_xor(s, o);
  float mu = s * (1.f / 192.f);
  float d0 = v0 - mu, d1 = v1 - mu, d2 = v2 - mu;
  float q2 = d0 * d0 + d1 * d1 + d2 * d2;
#pragma unroll
  for (int o = 32; o > 0; o >>= 1) q2 += __shfl_xor(q2, o);
  float rstd = rsqrtf(q2 * (1.f / 192.f) + 1e-5f);
  float xn0 = d0 * rstd * g[lane] + be[lane];
  float xn1 = d1 * rstd * g[lane + 64] + be[lane + 64];
  float xn2 = d2 * rstd * g[lane + 128] + be[lane + 128];
  u16* op = xnb + (size_t)row * CC;
  op[lane] = f2b(xn0); op[lane + 64] = f2b(xn1); op[lane + 128] = f2b(xn2);
  float qv[RC];
#pragma unroll
  for (int r = 0; r < RC; r++) {
    float t = xn0 * wq[lane * RC + r] + xn1 * wq[(lane + 64) * RC + r] + xn2 * wq[(lane + 128) * RC + r];
#pragma unroll
    for (int o = 32; o > 0; o >>= 1) t += __shfl_xor(t, o);
    qv[r] = t + wqb[r];
  }
  float nr = 0.f;
#pragma unroll
  for (int r = 0; r < RC; r++) nr += qv[r] * qv[r];
  float inv = 1.f / fmaxf(sqrtf(nr), 1e-12f);
  if (lane == 0) {
    float* qo = qn + (size_t)row * RC;
#pragma unroll
    for (int r = 0; r < RC; r++) qo[r] = qv[r] * inv;
  }
}

// ---------------- generic LN -> bf16 out ----------------
__global__ __launch_bounds__(256) void ln_kernel(const float* __restrict__ in,
                                                 u16* __restrict__ out,
                                                 const float* __restrict__ g,
                                                 const float* __restrict__ be) {
  int row = blockIdx.x * 4 + (threadIdx.x >> 6);
  int lane = threadIdx.x & 63;
  const float* p = in + (size_t)row * CC;
  float v0 = p[lane], v1 = p[lane + 64], v2 = p[lane + 128];
  float s = v0 + v1 + v2;
#pragma unroll
  for (int o = 32; o > 0; o >>= 1) s += __shfl_xor(s, o);
  float mu = s * (1.f / 192.f);
  float d0 = v0 - mu, d1 = v1 - mu, d2 = v2 - mu;
  float q2 = d0 * d0 + d1 * d1 + d2 * d2;
#pragma unroll
  for (int o = 32; o > 0; o >>= 1) q2 += __shfl_xor(q2, o);
  float rstd = rsqrtf(q2 * (1.f / 192.f) + 1e-5f);
  u16* op = out + (size_t)row * CC;
  op[lane]       = f2b(d0 * rstd * g[lane] + be[lane]);
  op[lane + 64]  = f2b(d1 * rstd * g[lane + 64] + be[lane + 64]);
  op[lane + 128] = f2b(d2 * rstd * g[lane + 128] + be[lane + 128]);
}

// ---------------- GEMM: A bf16 (row-major, lda=K), B f32 (ldb=Nn) ----------------
// EPI: 0 = store bf16 ; 1 = gelu + store bf16 ; 2 = f32 RMW add
template <int EPI>
__global__ __launch_bounds__(256) void gemm_bf(const u16* __restrict__ A,
                                               const float* __restrict__ Bw,
                                               const float* __restrict__ bias,
                                               void* __restrict__ Cv,
                                               int K, int Nn) {
  __shared__ float As[32][132];
  __shared__ float Bs[32][64];
  int tid = threadIdx.x;
  int m0 = blockIdx.x * 128, n0 = blockIdx.y * 64;
  float acc[8][4];
#pragma unroll
  for (int i = 0; i < 8; i++)
#pragma unroll
    for (int j = 0; j < 4; j++) acc[i][j] = 0.f;
  int arow = tid >> 1, akh = (tid & 1) * 16;
  int br = tid >> 4, bc4 = tid & 15;
  int ty = tid >> 4, tx = tid & 15;
  for (int k0 = 0; k0 < K; k0 += 32) {
    const uint4* ap = reinterpret_cast<const uint4*>(A + (size_t)(m0 + arow) * K + k0 + akh);
    uint4 a0 = ap[0], a1 = ap[1];
    float f[16];
    up8(a0, f); up8(a1, f + 8);
#pragma unroll
    for (int j = 0; j < 16; j++) As[akh + j][arow] = f[j];
#pragma unroll
    for (int i = 0; i < 2; i++) {
      float4 bv = *reinterpret_cast<const float4*>(Bw + (size_t)(k0 + br + 16 * i) * Nn + n0 + bc4 * 4);
      *reinterpret_cast<float4*>(&Bs[br + 16 * i][bc4 * 4]) = bv;
    }
    __syncthreads();
#pragma unroll
    for (int kk = 0; kk < 32; kk++) {
      float4 b4 = *reinterpret_cast<const float4*>(&Bs[kk][tx * 4]);
      float4 aA = *reinterpret_cast<const float4*>(&As[kk][ty * 8]);
      float4 aB = *reinterpret_cast<const float4*>(&As[kk][ty * 8 + 4]);
      acc[0][0] += aA.x * b4.x; acc[0][1] += aA.x * b4.y; acc[0][2] += aA.x * b4.z; acc[0][3] += aA.x * b4.w;
      acc[1][0] += aA.y * b4.x; acc[1][1] += aA.y * b4.y; acc[1][2] += aA.y * b4.z; acc[1][3] += aA.y * b4.w;
      acc[2][0] += aA.z * b4.x; acc[2][1] += aA.z * b4.y; acc[2][2] += aA.z * b4.z; acc[2][3] += aA.z * b4.w;
      acc[3][0] += aA.w * b4.x; acc[3][1] += aA.w * b4.y; acc[3][2] += aA.w * b4.z; acc[3][3] += aA.w * b4.w;
      acc[4][0] += aB.x * b4.x; acc[4][1] += aB.x * b4.y; acc[4][2] += aB.x * b4.z; acc[4][3] += aB.x * b4.w;
      acc[5][0] += aB.y * b4.x; acc[5][1] += aB.y * b4.y; acc[5][2] += aB.y * b4.z; acc[5][3] += aB.y * b4.w;
      acc[6][0] += aB.z * b4.x; acc[6][1] += aB.z * b4.y; acc[6][2] += aB.z * b4.z; acc[6][3] += aB.z * b4.w;
      acc[7][0] += aB.w * b4.x; acc[7][1] += aB.w * b4.y; acc[7][2] += aB.w * b4.z; acc[7][3] += aB.w * b4.w;
    }
    __syncthreads();
  }
  float4 bv = *reinterpret_cast<const float4*>(bias + n0 + tx * 4);
#pragma unroll
  for (int i = 0; i < 8; i++) {
    size_t off = (size_t)(m0 + ty * 8 + i) * Nn + n0 + tx * 4;
    float c0 = acc[i][0] + bv.x, c1 = acc[i][1] + bv.y, c2 = acc[i][2] + bv.z, c3 = acc[i][3] + bv.w;
    if constexpr (EPI == 2) {
      float* C = (float*)Cv;
      float4 o = *reinterpret_cast<float4*>(C + off);
      o.x += c0; o.y += c1; o.z += c2; o.w += c3;
      *reinterpret_cast<float4*>(C + off) = o;
    } else {
      if constexpr (EPI == 1) { c0 = gelu_f(c0); c1 = gelu_f(c1); c2 = gelu_f(c2); c3 = gelu_f(c3); }
      u16* C = (u16*)Cv;
      ushort4 sv;
      sv.x = f2b(c0); sv.y = f2b(c1); sv.z = f2b(c2); sv.w = f2b(c3);
      *reinterpret_cast<ushort4*>(C + off) = sv;
    }
  }
}

// ---------------- token-dictionary k/v projections (fp32, tiny) ----------------
__global__ __launch_bounds__(1024) void tdproj_kernel(const float* __restrict__ td,
                                                      const float* __restrict__ wk,
                                                      const float* __restrict__ wkb,
                                                      const float* __restrict__ wv,
                                                      const float* __restrict__ wvb,
                                                      const float* __restrict__ atd_scale,
                                                      float* __restrict__ knv,
                                                      float* __restrict__ vtd) {
  int b = blockIdx.x, tid = threadIdx.x;
  __shared__ float td_s[MM * CC];   // 48 KB
  __shared__ float k_s[MM][RC];
  const float* tdb = td + (size_t)b * MM * CC;
  for (int i = tid; i < MM * CC; i += 1024) td_s[i] = tdb[i];
  __syncthreads();
  for (int i = tid; i < MM * CC; i += 1024) {
    int m = i / CC, c = i % CC;
    float a = wvb[c];
    for (int r = 0; r < CC; r++) a += td_s[m * CC + r] * wv[r * CC + c];
    vtd[(size_t)b * MM * CC + i] = a;
  }
  for (int i = tid; i < MM * RC; i += 1024) {
    int m = i / RC, r = i % RC;
    float a = wkb[r];
    for (int c = 0; c < CC; c++) a += td_s[m * CC + c] * wk[c * RC + r];
    k_s[m][r] = a;
  }
  __syncthreads();
  if (tid < MM) {
    int m = tid;
    float nr = 0.f;
    for (int r = 0; r < RC; r++) nr += k_s[m][r] * k_s[m][r];
    float inv = 1.f / fmaxf(sqrtf(nr), 1e-12f);
    float sc = 1.f + fminf(fmaxf(atd_scale[m], 0.f), 1.f) * 4.1588830833596715f; // ln(64)
    for (int r = 0; r < RC; r++) knv[(size_t)b * MM * RC + m * RC + r] = k_s[m][r] * inv * sc;
  }
}

// ---------------- ATD cross attention (fp32): sim, tk_id, xacc = x + x_atd ----------------
__global__ __launch_bounds__(256, 2) void atd_kernel(const float* __restrict__ qn,
                                                     const float* __restrict__ x,
                                                     const float* __restrict__ knv,
                                                     const float* __restrict__ vtd,
                                                     float* __restrict__ sim,
                                                     int* __restrict__ tkid,
                                                     float* __restrict__ xacc) {
  __shared__ float v_s[MM][CC];   // 48 KB
  __shared__ float kn_s[MM][11];
  __shared__ float p_s[4][64];
  int tid = threadIdx.x;
  int b = (blockIdx.x * 64) / NN;
  float* vflat = &v_s[0][0];
  for (int i = tid; i < MM * CC; i += 256) vflat[i] = vtd[(size_t)b * MM * CC + i];
  for (int i = tid; i < MM * RC; i += 256) kn_s[i / RC][i % RC] = knv[(size_t)b * MM * RC + i];
  __syncthreads();
  int wave = tid >> 6, lane = tid & 63;
  for (int it = 0; it < 16; it++) {
    int tg = blockIdx.x * 64 + it * 4 + wave;
    const float* qr = qn + (size_t)tg * RC;
    float s = 0.f;
#pragma unroll
    for (int r = 0; r < RC; r++) s += qr[r] * kn_s[lane][r];
    float mx = s; int ai = lane;
#pragma unroll
    for (int o = 32; o > 0; o >>= 1) {
      float ov = __shfl_xor(mx, o); int oi = __shfl_xor(ai, o);
      if (ov > mx || (ov == mx && oi < ai)) { mx = ov; ai = oi; }
    }
    float e = __expf(s - mx);
    float sum = e;
#pragma unroll
    for (int o = 32; o > 0; o >>= 1) sum += __shfl_xor(sum, o);
    float p = e / sum;
    sim[(size_t)tg * MM + lane] = p;
    if (lane == 0) tkid[tg] = ai;
    p_s[wave][lane] = p;
    float a0 = 0.f, a1 = 0.f, a2 = 0.f;
#pragma unroll
    for (int m = 0; m < MM; m++) {
      float pm = p_s[wave][m];
      a0 += pm * v_s[m][lane];
      a1 += pm * v_s[m][lane + 64];
      a2 += pm * v_s[m][lane + 128];
    }
    const float* xr = x + (size_t)tg * CC;
    float* xo = xacc + (size_t)tg * CC;
    xo[lane]       = xr[lane]       + a0;
    xo[lane + 64]  = xr[lane + 64]  + a1;
    xo[lane + 128] = xr[lane + 128] + a2;
  }
}

// ---------------- stable counting sort of tk_id ----------------
__global__ void hist_kernel(const int* __restrict__ tkid, int* __restrict__ hist) {
  int i = blockIdx.x * 256 + threadIdx.x;
  if (i < BN) atomicAdd(&hist[(i / NN) * MM + tkid[i]], 1);
}

__global__ void scan_kernel(const int* __restrict__ hist, int* __restrict__ base) {
  int lane = threadIdx.x & 63, b = threadIdx.x >> 6;  // 128 threads
  int v = hist[b * MM + lane];
  int xx = v;
#pragma unroll
  for (int o = 1; o < 64; o <<= 1) { int t = __shfl_up(xx, o); if (lane >= o) xx += t; }
  base[b * MM + lane] = xx - v;
}

__global__ __launch_bounds__(256) void scatter_kernel(const int* __restrict__ tkid,
                                                      const int* __restrict__ base,
                                                      int* __restrict__ sort_idx) {
  int bk = blockIdx.x;
  int b = bk >> 6, key = bk & 63;
  int tid = threadIdx.x, wave = tid >> 6, lane = tid & 63;
  __shared__ int wtot[4];
  int offset = base[b * MM + key];
  const int* tk = tkid + (size_t)b * NN;
  for (int c0 = 0; c0 < NN; c0 += 256) {
    int i = c0 + tid;
    bool f = (tk[i] == key);
    unsigned long long mb = __ballot(f);
    int wpre = __popcll(mb & ((1ull << lane) - 1ull));
    if (lane == 0) wtot[wave] = __popcll(mb);
    __syncthreads();
    int pre = wpre;
#pragma unroll
    for (int w = 0; w < 4; w++) if (w < wave) pre += wtot[w];
    int tot = wtot[0] + wtot[1] + wtot[2] + wtot[3];
    if (f) sort_idx[(size_t)b * NN + offset + pre] = i;
    offset += tot;
    __syncthreads();
  }
}

// ---------------- AC_MSA grouped attention (qkv bf16) ----------------
__global__ __launch_bounds__(256, 2) void acmsa_kernel(const u16* __restrict__ qkv,
                                                       const int* __restrict__ sort_idx,
                                                       const float* __restrict__ logit_scale,
                                                       u16* __restrict__ ao) {
  __shared__ u16 Ks[GS][HD];
  __shared__ u16 Vs[GS][HD];
  int tid = threadIdx.x;
  int idx = blockIdx.x;
  int h = idx % NHEAD; idx /= NHEAD;
  int g = idx % NG;    idx /= NG;
  int b = idx;
  const int* sp = sort_idx + (size_t)b * NN + g * GS;
#pragma unroll
  for (int it = 0; it < 8; it++) {
    int li = tid + it * 256;
    int row = li >> 3, c4 = li & 7;
    size_t bas = ((size_t)b * NN + sp[row]) * 576 + h * HD + c4 * 4;
    *reinterpret_cast<ushort4*>(&Ks[row][c4 * 4]) = *reinterpret_cast<const ushort4*>(qkv + bas + CC);
    *reinterpret_cast<ushort4*>(&Vs[row][c4 * 4]) = *reinterpret_cast<const ushort4*>(qkv + bas + 2 * CC);
  }
  int mytok = sp[tid];
  float q[HD];
  {
    const uint4* qp = reinterpret_cast<const uint4*>(qkv + ((size_t)b * NN + mytok) * 576 + h * HD);
#pragma unroll
    for (int c8 = 0; c8 < 4; c8++) up8(qp[c8], q + c8 * 8);
  }
  float ls = __expf(fminf(logit_scale[0], 4.605170185988092f));
  __syncthreads();
  float mcur = -1e30f, l = 0.f, acc[HD];
#pragma unroll
  for (int c = 0; c < HD; c++) acc[c] = 0.f;
  for (int ch = 0; ch < 8; ch++) {
    float s[32];
    float cmax = -1e30f;
#pragma unroll
    for (int j = 0; j < 32; j++) {
      const uint4* kr = reinterpret_cast<const uint4*>(&Ks[ch * 32 + j][0]);
      float d = 0.f;
#pragma unroll
      for (int c8 = 0; c8 < 4; c8++) {
        float f[8]; up8(kr[c8], f);
#pragma unroll
        for (int t = 0; t < 8; t++) d += q[c8 * 8 + t] * f[t];
      }
      s[j] = d * ls;
      cmax = fmaxf(cmax, s[j]);
    }
    float mn = fmaxf(mcur, cmax);
    float corr = __expf(mcur - mn);
    l *= corr;
#pragma unroll
    for (int c = 0; c < HD; c++) acc[c] *= corr;
#pragma unroll
    for (int j = 0; j < 32; j++) {
      float p = __expf(s[j] - mn);
      l += p;
      const uint4* vr = reinterpret_cast<const uint4*>(&Vs[ch * 32 + j][0]);
#pragma unroll
      for (int c8 = 0; c8 < 4; c8++) {
        float f[8]; up8(vr[c8], f);
#pragma unroll
        for (int t = 0; t < 8; t++) acc[c8 * 8 + t] += p * f[t];
      }
    }
    mcur = mn;
  }
  float inv = 1.f / l;
  u16* ob = ao + ((size_t)b * NN + mytok) * 384 + h * HD;  // cols [0,192)
#pragma unroll
  for (int c = 0; c < HD; c += 4) {
    ushort4 sv;
    sv.x = f2b(acc[c] * inv); sv.y = f2b(acc[c + 1] * inv);
    sv.z = f2b(acc[c + 2] * inv); sv.w = f2b(acc[c + 3] * inv);
    *reinterpret_cast<ushort4*>(ob + c) = sv;
  }
}

// ---------------- rpb gather ----------------
__global__ void rpb_kernel(const int* __restrict__ rpi, const float* __restrict__ table,
                           float* __restrict__ rpbf) {
  int ij = blockIdx.x * 256 + threadIdx.x;  // 65536
  int idx = rpi[ij];
#pragma unroll
  for (int h = 0; h < NHEAD; h++) rpbf[h * 65536 + ij] = table[idx * NHEAD + h];
}

// ---------------- shifted-window MSA (qkv bf16) ----------------
__device__ __forceinline__ int win_token(int wy, int wx, int i) {
  int iy = i >> 4, ix = i & 15;
  int sy = (wy * 16 + iy + 8) % 192;
  int sx = (wx * 16 + ix + 8) % 192;
  return sy * 192 + sx;
}

__global__ __launch_bounds__(256, 2) void winmsa_kernel(const u16* __restrict__ qkv,
                                                        const float* __restrict__ rpbf,
                                                        const float* __restrict__ mask,
                                                        u16* __restrict__ ao) {
  __shared__ u16 Ks[GS][HD];
  __shared__ u16 Vs[GS][HD];
  int tid = threadIdx.x;
  int idx = blockIdx.x;
  int h = idx % NHEAD; idx /= NHEAD;
  int wx = idx % 12;   idx /= 12;
  int wy = idx % 12;   idx /= 12;
  int b = idx;
#pragma unroll
  for (int it = 0; it < 8; it++) {
    int li = tid + it * 256;
    int row = li >> 3, c4 = li & 7;
    size_t bas = ((size_t)b * NN + win_token(wy, wx, row)) * 576 + h * HD + c4 * 4;
    *reinterpret_cast<ushort4*>(&Ks[row][c4 * 4]) = *reinterpret_cast<const ushort4*>(qkv + bas + CC);
    *reinterpret_cast<ushort4*>(&Vs[row][c4 * 4]) = *reinterpret_cast<const ushort4*>(qkv + bas + 2 * CC);
  }
  int mytok = win_token(wy, wx, tid);
  float q[HD];
  {
    const uint4* qp = reinterpret_cast<const uint4*>(qkv + ((size_t)b * NN + mytok) * 576 + h * HD);
#pragma unroll
    for (int c8 = 0; c8 < 4; c8++) up8(qp[c8], q + c8 * 8);
#pragma unroll
    for (int c = 0; c < HD; c++) q[c] *= 0.17677669529663687f;
  }
  const float* rpbrow = rpbf + h * 65536 + tid * 256;
  const float* mrow = mask + (size_t)(wy * 12 + wx) * 65536 + tid * 256;
  __syncthreads();
  float mcur = -1e30f, l = 0.f, acc[HD];
#pragma unroll
  for (int c = 0; c < HD; c++) acc[c] = 0.f;
  for (int ch = 0; ch < 8; ch++) {
    float s[32];
    float cmax = -1e30f;
#pragma unroll
    for (int j = 0; j < 32; j++) {
      const uint4* kr = reinterpret_cast<const uint4*>(&Ks[ch * 32 + j][0]);
      float d = 0.f;
#pragma unroll
      for (int c8 = 0; c8 < 4; c8++) {
        float f[8]; up8(kr[c8], f);
#pragma unroll
        for (int t = 0; t < 8; t++) d += q[c8 * 8 + t] * f[t];
      }
      s[j] = d + rpbrow[ch * 32 + j] + mrow[ch * 32 + j];
      cmax = fmaxf(cmax, s[j]);
    }
    float mn = fmaxf(mcur, cmax);
    float corr = __expf(mcur - mn);
    l *= corr;
#pragma unroll
    for (int c = 0; c < HD; c++) acc[c] *= corr;
#pragma unroll
    for (int j = 0; j < 32; j++) {
      float p = __expf(s[j] - mn);
      l += p;
      const uint4* vr = reinterpret_cast<const uint4*>(&Vs[ch * 32 + j][0]);
#pragma unroll
      for (int c8 = 0; c8 < 4; c8++) {
        float f[8]; up8(vr[c8], f);
#pragma unroll
        for (int t = 0; t < 8; t++) acc[c8 * 8 + t] += p * f[t];
      }
    }
    mcur = mn;
  }
  float inv = 1.f / l;
  u16* ob = ao + ((size_t)b * NN + mytok) * 384 + CC + h * HD;  // cols [192,384)
#pragma unroll
  for (int c = 0; c < HD; c += 4) {
    ushort4 sv;
    sv.x = f2b(acc[c] * inv); sv.y = f2b(acc[c + 1] * inv);
    sv.z = f2b(acc[c + 2] * inv); sv.w = f2b(acc[c + 3] * inv);
    *reinterpret_cast<ushort4*>(ob + c) = sv;
  }
}

// ---------------- concat proj weights / biases ----------------
__global__ void prep_kernel(const float* __restrict__ pa_w, const float* __restrict__ pw_w,
                            const float* __restrict__ pa_b, const float* __restrict__ pw_b,
                            float* __restrict__ wcat, float* __restrict__ bcat) {
  int i = blockIdx.x * 256 + threadIdx.x;  // 73728
  int k = i / 192, n = i % 192;
  wcat[i] = (k < 192) ? pa_w[k * 192 + n] : pw_w[(k - 192) * 192 + n];
  if (i < 192) bcat[i] = pa_b[i] + pw_b[i];
}

// ---------------- depthwise 5x5 conv + gelu + residual (bf16 in/out) ----------------
__global__ __launch_bounds__(384) void dwconv_kernel(const u16* __restrict__ y2,
                                                     const float* __restrict__ dww,
                                                     const float* __restrict__ dwb,
                                                     u16* __restrict__ y2pc) {
  int c = threadIdx.x;
  int p = blockIdx.x;
  int x = p % WW;
  int y = (p / WW) % HH;
  int b = p / (HH * WW);
  const float* w = dww + c * 25;
  float a = 0.f;
#pragma unroll
  for (int dy = 0; dy < 5; dy++) {
    int yy = y + dy - 2;
    if (yy < 0 || yy >= HH) continue;
#pragma unroll
    for (int dx = 0; dx < 5; dx++) {
      int xx = x + dx - 2;
      if (xx < 0 || xx >= WW) continue;
      a += b2f(y2[((size_t)b * NN + yy * WW + xx) * HID + c]) * w[dy * 5 + dx];
    }
  }
  float gl = gelu_f(a + dwb[c]);
  size_t o = ((size_t)b * NN + y * WW + x) * HID + c;
  y2pc[o] = f2b(b2f(y2[o]) + gl);
}

// ---------------- td refinement ----------------
__global__ __launch_bounds__(256) void zsum_kernel(const float* __restrict__ sim,
                                                   float* __restrict__ Z) {
  int blk = blockIdx.x;
  int b = blk / NG;
  int n0 = (blk % NG) * 256;
  int tid = threadIdx.x, m = tid & 63, sub = tid >> 6;
  float a = 0.f;
  const float* sp = sim + ((size_t)b * NN + n0) * MM;
  for (int n = sub; n < 256; n += 4) a += __expf(sp[n * MM + m]);
  __shared__ float red[4][64];
  red[sub][m] = a;
  __syncthreads();
  if (tid < 64) atomicAdd(&Z[b * MM + m], red[0][m] + red[1][m] + red[2][m] + red[3][m]);
}

__global__ void invz_kernel(const float* __restrict__ Z, float* __restrict__ invZ) {
  int i = threadIdx.x;  // 128
  invZ[i] = 1.f / Z[i];
}

__global__ __launch_bounds__(192, 2) void tdacc_kernel(const float* __restrict__ sim,
                                                       const float* __restrict__ invZ,
                                                       const u16* __restrict__ ln3x,
                                                       float* __restrict__ tdacc) {
  __shared__ u16 w_s[256][64];  // 32 KB
  int blk = blockIdx.x;
  int b = blk / NG;
  int n0 = (blk % NG) * 256;
  int tid = threadIdx.x;
  const float* sp = sim + ((size_t)b * NN + n0) * MM;
  const float* iz = invZ + b * MM;
  for (int i = tid; i < 256 * 64; i += 192)
    w_s[i >> 6][i & 63] = f2b(__expf(sp[i]) * iz[i & 63]);
  __syncthreads();
  float acc[64];
#pragma unroll
  for (int m = 0; m < 64; m++) acc[m] = 0.f;
  const u16* lp = ln3x + ((size_t)b * NN + n0) * CC + tid;
  for (int n = 0; n < 256; n++) {
    float val = b2f(lp[(size_t)n * CC]);
    const uint4* wr = reinterpret_cast<const uint4*>(&w_s[n][0]);
#pragma unroll
    for (int c8 = 0; c8 < 8; c8++) {
      float f[8]; up8(wr[c8], f);
#pragma unroll
      for (int t = 0; t < 8; t++) acc[c8 * 8 + t] += f[t] * val;
    }
  }
  for (int m = 0; m < 64; m++) atomicAdd(&tdacc[((size_t)b * MM + m) * CC + tid], acc[m]);
}

__global__ void tdfin_kernel(const float* __restrict__ td, const float* __restrict__ sigma,
                             const float* __restrict__ tdacc, float* __restrict__ out) {
  int i = blockIdx.x * 256 + threadIdx.x;  // 24576
  if (i >= BB * MM * CC) return;
  int m = (i / CC) % MM;
  float s = 1.f / (1.f + __expf(-sigma[m]));
  out[i] = s * td[i] + (1.f - s) * tdacc[i];
}

// ---------------- workspace layout (bytes) ----------------
static constexpr size_t oQKV = 0;                                   // u16 BN*576 (later y2 bf16)
static constexpr size_t oXN  = oQKV + (size_t)BN * 576 * 2;         // u16 BN*192 (xn1/xn2/ln3x)
static constexpr size_t oAO  = oXN  + (size_t)BN * CC * 2;          // u16 BN*384 (aca|win; later y2pc)
static constexpr size_t oSIM = oAO  + (size_t)BN * 384 * 2;         // f32 BN*64
static constexpr size_t oQN  = oSIM + (size_t)BN * MM * 4;          // f32 BN*10
static constexpr size_t oRPB = oQN  + (size_t)BN * RC * 4;          // f32 6*65536
static constexpr size_t oVTD = oRPB + (size_t)6 * 65536 * 4;        // f32 BB*MM*CC
static constexpr size_t oKNV = oVTD + (size_t)BB * MM * CC * 4;     // f32 BB*MM*RC
static constexpr size_t oWC  = oKNV + (size_t)BB * MM * RC * 4;     // f32 384*192
static constexpr size_t oBC  = oWC  + (size_t)384 * 192 * 4;        // f32 192 (pad to 1024)
static constexpr size_t oTK  = oBC  + 1024;                         // int BN
static constexpr size_t oSORT= oTK  + (size_t)BN * 4;               // int BN
static constexpr size_t oHIST= oSORT+ (size_t)BN * 4;               // int 128   } contiguous,
static constexpr size_t oBASE= oHIST+ 512;                          // int 128   } zeroed by
static constexpr size_t oZ   = oBASE+ 512;                          // f32 128   } zero_kernel
static constexpr size_t oTDA = oZ   + 512;                          // f32 BB*MM*CC }
static constexpr size_t oINV = oTDA + (size_t)BB * MM * CC * 4;     // f32 128
static constexpr size_t WS_NEEDED = oINV + 512;                     // ~194.4 MB

extern "C" void kernel_launch(void* const* d_in, const int* in_sizes, int n_in,
                              void* d_out, int out_size, void* d_ws, size_t ws_size,
                              hipStream_t stream) {
  if (ws_size < WS_NEEDED) return;  // diagnostic tripwire: clean absmax-fail instead of fault
  const float* x       = (const float*)d_in[0];
  const float* td      = (const float*)d_in[1];
  const int*   rpi     = (const int*)d_in[2];
  const float* amask   = (const float*)d_in[3];
  const float* n1g     = (const float*)d_in[6];
  const float* n1b     = (const float*)d_in[7];
  const float* n2g     = (const float*)d_in[8];
  const float* n2b     = (const float*)d_in[9];
  const float* n3g     = (const float*)d_in[10];
  const float* n3b     = (const float*)d_in[11];
  const float* wqkv_w  = (const float*)d_in[12];
  const float* wqkv_b  = (const float*)d_in[13];
  const float* wq_w    = (const float*)d_in[14];
  const float* wq_b    = (const float*)d_in[15];
  const float* wk_w    = (const float*)d_in[16];
  const float* wk_b    = (const float*)d_in[17];
  const float* wv_w    = (const float*)d_in[18];
  const float* wv_b    = (const float*)d_in[19];
  const float* atd_sc  = (const float*)d_in[20];
  const float* paca_w  = (const float*)d_in[21];
  const float* paca_b  = (const float*)d_in[22];
  const float* lgsc    = (const float*)d_in[23];
  const float* rpb_tab = (const float*)d_in[24];
  const float* pwin_w  = (const float*)d_in[25];
  const float* pwin_b  = (const float*)d_in[26];
  const float* fc1_w   = (const float*)d_in[27];
  const float* fc1_b   = (const float*)d_in[28];
  const float* dw_w    = (const float*)d_in[29];
  const float* dw_b    = (const float*)d_in[30];
  const float* fc2_w   = (const float*)d_in[31];
  const float* fc2_b   = (const float*)d_in[32];
  const float* sigma   = (const float*)d_in[33];
  float* out = (float*)d_out;
  char* wsb = (char*)d_ws;

  u16*   QKVb = (u16*)(wsb + oQKV);
  u16*   XNb  = (u16*)(wsb + oXN);
  u16*   AOb  = (u16*)(wsb + oAO);
  float* SIM  = (float*)(wsb + oSIM);
  float* QN   = (float*)(wsb + oQN);
  float* RPB  = (float*)(wsb + oRPB);
  float* VTD  = (float*)(wsb + oVTD);
  float* KNV  = (float*)(wsb + oKNV);
  float* WC   = (float*)(wsb + oWC);
  float* BC   = (float*)(wsb + oBC);
  int*   TK   = (int*)(wsb + oTK);
  int*   SORT = (int*)(wsb + oSORT);
  int*   HIST = (int*)(wsb + oHIST);
  int*   BASE = (int*)(wsb + oBASE);
  float* Z    = (float*)(wsb + oZ);
  float* TDA  = (float*)(wsb + oTDA);
  float* INVZ = (float*)(wsb + oINV);

  zero_kernel<<<98, 256, 0, stream>>>(HIST, 24960);  // hist+base+Z+tdacc
  ln1_kernel<<<BN / 4, 256, 0, stream>>>(x, n1g, n1b, wq_w, wq_b, XNb, QN);
  tdproj_kernel<<<BB, 1024, 0, stream>>>(td, wk_w, wk_b, wv_w, wv_b, atd_sc, KNV, VTD);
  gemm_bf<0><<<dim3(BN / 128, 9), 256, 0, stream>>>(XNb, wqkv_w, wqkv_b, QKVb, 192, 576);
  atd_kernel<<<BN / 64, 256, 0, stream>>>(QN, x, KNV, VTD, SIM, TK, out);
  hist_kernel<<<BN / 256, 256, 0, stream>>>(TK, HIST);
  scan_kernel<<<1, 128, 0, stream>>>(HIST, BASE);
  scatter_kernel<<<BB * MM, 256, 0, stream>>>(TK, BASE, SORT);
  acmsa_kernel<<<BB * NG * NHEAD, 256, 0, stream>>>(QKVb, SORT, lgsc, AOb);
  rpb_kernel<<<256, 256, 0, stream>>>(rpi, rpb_tab, RPB);
  winmsa_kernel<<<BB * NG * NHEAD, 256, 0, stream>>>(QKVb, RPB, amask, AOb);
  prep_kernel<<<288, 256, 0, stream>>>(paca_w, pwin_w, paca_b, pwin_b, WC, BC);
  gemm_bf<2><<<dim3(BN / 128, 3), 256, 0, stream>>>(AOb, WC, BC, out, 384, 192);
  ln_kernel<<<BN / 4, 256, 0, stream>>>(out, XNb, n2g, n2b);
  gemm_bf<1><<<dim3(BN / 128, 6), 256, 0, stream>>>(XNb, fc1_w, fc1_b, QKVb, 192, 384);
  dwconv_kernel<<<BB * HH * WW, 384, 0, stream>>>(QKVb, dw_w, dw_b, AOb);
  gemm_bf<2><<<dim3(BN / 128, 3), 256, 0, stream>>>(AOb, fc2_w, fc2_b, out, 384, 192);
  ln_kernel<<<BN / 4, 256, 0, stream>>>(out, XNb, n3g, n3b);
  zsum_kernel<<<BB * NG, 256, 0, stream>>>(SIM, Z);
  invz_kernel<<<1, 128, 0, stream>>>(Z, INVZ);
  tdacc_kernel<<<BB * NG, 192, 0, stream>>>(SIM, INVZ, XNb, TDA);
  tdfin_kernel<<<96, 256, 0, stream>>>(td, sigma, TDA, out + (size_t)BN * CC);
}

// Round 6
// 2747.442 us; speedup vs baseline: 2.2034x; 2.2034x over previous
//
#include <hip/hip_runtime.h>
#include <math.h>

// ---------------- problem constants ----------------
#define BB 2
#define HH 192
#define WW 192
#define NN 36864
#define CC 192
#define NHEAD 6
#define HD 32
#define MM 64
#define RC 10
#define GS 256
#define NG 144
#define HID 384
#define BN 73728

typedef unsigned short u16;
typedef __attribute__((ext_vector_type(8))) short short8;
typedef __attribute__((ext_vector_type(4))) float f32x4;

__device__ __forceinline__ float b2f(u16 u) { return __uint_as_float(((unsigned)u) << 16); }
__device__ __forceinline__ u16 f2b(float f) {
  unsigned v = __float_as_uint(f);
  return (u16)((v + 0x7fffu + ((v >> 16) & 1u)) >> 16);
}
__device__ __forceinline__ void up8(uint4 u, float* f) {
  f[0] = __uint_as_float(u.x << 16); f[1] = __uint_as_float(u.x & 0xffff0000u);
  f[2] = __uint_as_float(u.y << 16); f[3] = __uint_as_float(u.y & 0xffff0000u);
  f[4] = __uint_as_float(u.z << 16); f[5] = __uint_as_float(u.z & 0xffff0000u);
  f[6] = __uint_as_float(u.w << 16); f[7] = __uint_as_float(u.w & 0xffff0000u);
}
__device__ __forceinline__ float gelu_f(float v) {
  return 0.5f * v * (1.f + erff(v * 0.70710678118654752f));
}

// ---------------- zero scratch ----------------
__global__ void zero_kernel(int* __restrict__ p, int n) {
  int i = blockIdx.x * 256 + threadIdx.x;
  if (i < n) p[i] = 0;
}

// ---------------- LN1 fused with ATD q projection (fp32 path) ----------------
__global__ __launch_bounds__(256) void ln1_kernel(const float* __restrict__ x,
                                                  const float* __restrict__ g,
                                                  const float* __restrict__ be,
                                                  const float* __restrict__ wq,
                                                  const float* __restrict__ wqb,
                                                  u16* __restrict__ xnb,
                                                  float* __restrict__ qn) {
  int row = blockIdx.x * 4 + (threadIdx.x >> 6);
  int lane = threadIdx.x & 63;
  const float* p = x + (size_t)row * CC;
  float v0 = p[lane], v1 = p[lane + 64], v2 = p[lane + 128];
  float s = v0 + v1 + v2;
#pragma unroll
  for (int o = 32; o > 0; o >>= 1) s += __shfl_xor(s, o);
  float mu = s * (1.f / 192.f);
  float d0 = v0 - mu, d1 = v1 - mu, d2 = v2 - mu;
  float q2 = d0 * d0 + d1 * d1 + d2 * d2;
#pragma unroll
  for (int o = 32; o > 0; o >>= 1) q2 += __shfl_xor(q2, o);
  float rstd = rsqrtf(q2 * (1.f / 192.f) + 1e-5f);
  float xn0 = d0 * rstd * g[lane] + be[lane];
  float xn1 = d1 * rstd * g[lane + 64] + be[lane + 64];
  float xn2 = d2 * rstd * g[lane + 128] + be[lane + 128];
  u16* op = xnb + (size_t)row * CC;
  op[lane] = f2b(xn0); op[lane + 64] = f2b(xn1); op[lane + 128] = f2b(xn2);
  float qv[RC];
#pragma unroll
  for (int r = 0; r < RC; r++) {
    float t = xn0 * wq[lane * RC + r] + xn1 * wq[(lane + 64) * RC + r] + xn2 * wq[(lane + 128) * RC + r];
#pragma unroll
    for (int o = 32; o > 0; o >>= 1) t += __shfl_xor(t, o);
    qv[r] = t + wqb[r];
  }
  float nr = 0.f;
#pragma unroll
  for (int r = 0; r < RC; r++) nr += qv[r] * qv[r];
  float inv = 1.f / fmaxf(sqrtf(nr), 1e-12f);
  if (lane == 0) {
    float* qo = qn + (size_t)row * RC;
#pragma unroll
    for (int r = 0; r < RC; r++) qo[r] = qv[r] * inv;
  }
}

// ---------------- generic LN -> bf16 out ----------------
__global__ __launch_bounds__(256) void ln_kernel(const float* __restrict__ in,
                                                 u16* __restrict__ out,
                                                 const float* __restrict__ g,
                                                 const float* __restrict__ be) {
  int row = blockIdx.x * 4 + (threadIdx.x >> 6);
  int lane = threadIdx.x & 63;
  const float* p = in + (size_t)row * CC;
  float v0 = p[lane], v1 = p[lane + 64], v2 = p[lane + 128];
  float s = v0 + v1 + v2;
#pragma unroll
  for (int o = 32; o > 0; o >>= 1) s += __shfl_xor(s, o);
  float mu = s * (1.f / 192.f);
  float d0 = v0 - mu, d1 = v1 - mu, d2 = v2 - mu;
  float q2 = d0 * d0 + d1 * d1 + d2 * d2;
#pragma unroll
  for (int o = 32; o > 0; o >>= 1) q2 += __shfl_xor(q2, o);
  float rstd = rsqrtf(q2 * (1.f / 192.f) + 1e-5f);
  u16* op = out + (size_t)row * CC;
  op[lane]       = f2b(d0 * rstd * g[lane] + be[lane]);
  op[lane + 64]  = f2b(d1 * rstd * g[lane + 64] + be[lane + 64]);
  op[lane + 128] = f2b(d2 * rstd * g[lane + 128] + be[lane + 128]);
}

// ---------------- GEMM: A bf16 (row-major, lda=K), B f32 (ldb=Nn) ----------------
// EPI: 0 = store bf16 ; 1 = gelu + store bf16 ; 2 = f32 RMW add
template <int EPI>
__global__ __launch_bounds__(256) void gemm_bf(const u16* __restrict__ A,
                                               const float* __restrict__ Bw,
                                               const float* __restrict__ bias,
                                               void* __restrict__ Cv,
                                               int K, int Nn) {
  __shared__ float As[32][132];
  __shared__ float Bs[32][64];
  int tid = threadIdx.x;
  int m0 = blockIdx.x * 128, n0 = blockIdx.y * 64;
  float acc[8][4];
#pragma unroll
  for (int i = 0; i < 8; i++)
#pragma unroll
    for (int j = 0; j < 4; j++) acc[i][j] = 0.f;
  int arow = tid >> 1, akh = (tid & 1) * 16;
  int br = tid >> 4, bc4 = tid & 15;
  int ty = tid >> 4, tx = tid & 15;
  for (int k0 = 0; k0 < K; k0 += 32) {
    const uint4* ap = reinterpret_cast<const uint4*>(A + (size_t)(m0 + arow) * K + k0 + akh);
    uint4 a0 = ap[0], a1 = ap[1];
    float f[16];
    up8(a0, f); up8(a1, f + 8);
#pragma unroll
    for (int j = 0; j < 16; j++) As[akh + j][arow] = f[j];
#pragma unroll
    for (int i = 0; i < 2; i++) {
      float4 bv = *reinterpret_cast<const float4*>(Bw + (size_t)(k0 + br + 16 * i) * Nn + n0 + bc4 * 4);
      *reinterpret_cast<float4*>(&Bs[br + 16 * i][bc4 * 4]) = bv;
    }
    __syncthreads();
#pragma unroll
    for (int kk = 0; kk < 32; kk++) {
      float4 b4 = *reinterpret_cast<const float4*>(&Bs[kk][tx * 4]);
      float4 aA = *reinterpret_cast<const float4*>(&As[kk][ty * 8]);
      float4 aB = *reinterpret_cast<const float4*>(&As[kk][ty * 8 + 4]);
      acc[0][0] += aA.x * b4.x; acc[0][1] += aA.x * b4.y; acc[0][2] += aA.x * b4.z; acc[0][3] += aA.x * b4.w;
      acc[1][0] += aA.y * b4.x; acc[1][1] += aA.y * b4.y; acc[1][2] += aA.y * b4.z; acc[1][3] += aA.y * b4.w;
      acc[2][0] += aA.z * b4.x; acc[2][1] += aA.z * b4.y; acc[2][2] += aA.z * b4.z; acc[2][3] += aA.z * b4.w;
      acc[3][0] += aA.w * b4.x; acc[3][1] += aA.w * b4.y; acc[3][2] += aA.w * b4.z; acc[3][3] += aA.w * b4.w;
      acc[4][0] += aB.x * b4.x; acc[4][1] += aB.x * b4.y; acc[4][2] += aB.x * b4.z; acc[4][3] += aB.x * b4.w;
      acc[5][0] += aB.y * b4.x; acc[5][1] += aB.y * b4.y; acc[5][2] += aB.y * b4.z; acc[5][3] += aB.y * b4.w;
      acc[6][0] += aB.z * b4.x; acc[6][1] += aB.z * b4.y; acc[6][2] += aB.z * b4.z; acc[6][3] += aB.z * b4.w;
      acc[7][0] += aB.w * b4.x; acc[7][1] += aB.w * b4.y; acc[7][2] += aB.w * b4.z; acc[7][3] += aB.w * b4.w;
    }
    __syncthreads();
  }
  float4 bv = *reinterpret_cast<const float4*>(bias + n0 + tx * 4);
#pragma unroll
  for (int i = 0; i < 8; i++) {
    size_t off = (size_t)(m0 + ty * 8 + i) * Nn + n0 + tx * 4;
    float c0 = acc[i][0] + bv.x, c1 = acc[i][1] + bv.y, c2 = acc[i][2] + bv.z, c3 = acc[i][3] + bv.w;
    if constexpr (EPI == 2) {
      float* C = (float*)Cv;
      float4 o = *reinterpret_cast<float4*>(C + off);
      o.x += c0; o.y += c1; o.z += c2; o.w += c3;
      *reinterpret_cast<float4*>(C + off) = o;
    } else {
      if constexpr (EPI == 1) { c0 = gelu_f(c0); c1 = gelu_f(c1); c2 = gelu_f(c2); c3 = gelu_f(c3); }
      u16* C = (u16*)Cv;
      ushort4 sv;
      sv.x = f2b(c0); sv.y = f2b(c1); sv.z = f2b(c2); sv.w = f2b(c3);
      *reinterpret_cast<ushort4*>(C + off) = sv;
    }
  }
}

// ---------------- token-dictionary k/v projections (fp32, tiny) ----------------
__global__ __launch_bounds__(1024) void tdproj_kernel(const float* __restrict__ td,
                                                      const float* __restrict__ wk,
                                                      const float* __restrict__ wkb,
                                                      const float* __restrict__ wv,
                                                      const float* __restrict__ wvb,
                                                      const float* __restrict__ atd_scale,
                                                      float* __restrict__ knv,
                                                      float* __restrict__ vtd) {
  int b = blockIdx.x, tid = threadIdx.x;
  __shared__ float td_s[MM * CC];   // 48 KB
  __shared__ float k_s[MM][RC];
  const float* tdb = td + (size_t)b * MM * CC;
  for (int i = tid; i < MM * CC; i += 1024) td_s[i] = tdb[i];
  __syncthreads();
  for (int i = tid; i < MM * CC; i += 1024) {
    int m = i / CC, c = i % CC;
    float a = wvb[c];
    for (int r = 0; r < CC; r++) a += td_s[m * CC + r] * wv[r * CC + c];
    vtd[(size_t)b * MM * CC + i] = a;
  }
  for (int i = tid; i < MM * RC; i += 1024) {
    int m = i / RC, r = i % RC;
    float a = wkb[r];
    for (int c = 0; c < CC; c++) a += td_s[m * CC + c] * wk[c * RC + r];
    k_s[m][r] = a;
  }
  __syncthreads();
  if (tid < MM) {
    int m = tid;
    float nr = 0.f;
    for (int r = 0; r < RC; r++) nr += k_s[m][r] * k_s[m][r];
    float inv = 1.f / fmaxf(sqrtf(nr), 1e-12f);
    float sc = 1.f + fminf(fmaxf(atd_scale[m], 0.f), 1.f) * 4.1588830833596715f; // ln(64)
    for (int r = 0; r < RC; r++) knv[(size_t)b * MM * RC + m * RC + r] = k_s[m][r] * inv * sc;
  }
}

// ---------------- ATD cross attention (fp32): sim, tk_id, xacc = x + x_atd ----------------
__global__ __launch_bounds__(256, 2) void atd_kernel(const float* __restrict__ qn,
                                                     const float* __restrict__ x,
                                                     const float* __restrict__ knv,
                                                     const float* __restrict__ vtd,
                                                     float* __restrict__ sim,
                                                     int* __restrict__ tkid,
                                                     float* __restrict__ xacc) {
  __shared__ float v_s[MM][CC];   // 48 KB
  __shared__ float kn_s[MM][11];
  __shared__ float p_s[4][64];
  int tid = threadIdx.x;
  int b = (blockIdx.x * 64) / NN;
  float* vflat = &v_s[0][0];
  for (int i = tid; i < MM * CC; i += 256) vflat[i] = vtd[(size_t)b * MM * CC + i];
  for (int i = tid; i < MM * RC; i += 256) kn_s[i / RC][i % RC] = knv[(size_t)b * MM * RC + i];
  __syncthreads();
  int wave = tid >> 6, lane = tid & 63;
  for (int it = 0; it < 16; it++) {
    int tg = blockIdx.x * 64 + it * 4 + wave;
    const float* qr = qn + (size_t)tg * RC;
    float s = 0.f;
#pragma unroll
    for (int r = 0; r < RC; r++) s += qr[r] * kn_s[lane][r];
    float mx = s; int ai = lane;
#pragma unroll
    for (int o = 32; o > 0; o >>= 1) {
      float ov = __shfl_xor(mx, o); int oi = __shfl_xor(ai, o);
      if (ov > mx || (ov == mx && oi < ai)) { mx = ov; ai = oi; }
    }
    float e = __expf(s - mx);
    float sum = e;
#pragma unroll
    for (int o = 32; o > 0; o >>= 1) sum += __shfl_xor(sum, o);
    float p = e / sum;
    sim[(size_t)tg * MM + lane] = p;
    if (lane == 0) tkid[tg] = ai;
    p_s[wave][lane] = p;
    float a0 = 0.f, a1 = 0.f, a2 = 0.f;
#pragma unroll
    for (int m = 0; m < MM; m++) {
      float pm = p_s[wave][m];
      a0 += pm * v_s[m][lane];
      a1 += pm * v_s[m][lane + 64];
      a2 += pm * v_s[m][lane + 128];
    }
    const float* xr = x + (size_t)tg * CC;
    float* xo = xacc + (size_t)tg * CC;
    xo[lane]       = xr[lane]       + a0;
    xo[lane + 64]  = xr[lane + 64]  + a1;
    xo[lane + 128] = xr[lane + 128] + a2;
  }
}

// ---------------- stable counting sort of tk_id ----------------
__global__ void hist_kernel(const int* __restrict__ tkid, int* __restrict__ hist) {
  int i = blockIdx.x * 256 + threadIdx.x;
  if (i < BN) atomicAdd(&hist[(i / NN) * MM + tkid[i]], 1);
}

__global__ void scan_kernel(const int* __restrict__ hist, int* __restrict__ base) {
  int lane = threadIdx.x & 63, b = threadIdx.x >> 6;  // 128 threads
  int v = hist[b * MM + lane];
  int xx = v;
#pragma unroll
  for (int o = 1; o < 64; o <<= 1) { int t = __shfl_up(xx, o); if (lane >= o) xx += t; }
  base[b * MM + lane] = xx - v;
}

__global__ __launch_bounds__(256) void scatter_kernel(const int* __restrict__ tkid,
                                                      const int* __restrict__ base,
                                                      int* __restrict__ sort_idx) {
  int bk = blockIdx.x;
  int b = bk >> 6, key = bk & 63;
  int tid = threadIdx.x, wave = tid >> 6, lane = tid & 63;
  __shared__ int wtot[4];
  int offset = base[b * MM + key];
  const int* tk = tkid + (size_t)b * NN;
  for (int c0 = 0; c0 < NN; c0 += 256) {
    int i = c0 + tid;
    bool f = (tk[i] == key);
    unsigned long long mb = __ballot(f);
    int wpre = __popcll(mb & ((1ull << lane) - 1ull));
    if (lane == 0) wtot[wave] = __popcll(mb);
    __syncthreads();
    int pre = wpre;
#pragma unroll
    for (int w = 0; w < 4; w++) if (w < wave) pre += wtot[w];
    int tot = wtot[0] + wtot[1] + wtot[2] + wtot[3];
    if (f) sort_idx[(size_t)b * NN + offset + pre] = i;
    offset += tot;
    __syncthreads();
  }
}

// ---------------- rpb gather ----------------
__global__ void rpb_kernel(const int* __restrict__ rpi, const float* __restrict__ table,
                           float* __restrict__ rpbf) {
  int ij = blockIdx.x * 256 + threadIdx.x;  // 65536
  int idx = rpi[ij];
#pragma unroll
  for (int h = 0; h < NHEAD; h++) rpbf[h * 65536 + ij] = table[idx * NHEAD + h];
}

// ---------------- MFMA attention (shared by AC_MSA and window MSA) ----------------
// MODE 0 = acmsa (sorted-token groups, logit_scale), MODE 1 = winmsa (rpb + mask)
// block = (b, group/window, head); 4 waves x 64 queries; KV chunked by 64 keys.
// v_mfma_f32_16x16x32_bf16 layouts: A: row=lane&15, k=8*(lane>>4)+j;
// B: col=lane&15, k=8*(lane>>4)+j; C/D: col=lane&15, row=4*(lane>>4)+reg [HW-verified].
template <int MODE>
__global__ __launch_bounds__(256, 2) void attn_mfma_kernel(const u16* __restrict__ qkv,
                                                           const int* __restrict__ sort_idx,
                                                           const float* __restrict__ lgsc,
                                                           const float* __restrict__ rpbf,
                                                           const float* __restrict__ amask,
                                                           u16* __restrict__ ao) {
  __shared__ u16 Ks[GS][40];       // [token][ch] pad->40 (2-way conflict = free)
  __shared__ u16 Vt[HD][GS + 8];   // [ch][token] transposed, pad->264
  __shared__ u16 Ps[4][64][72];    // per-wave P round-trip, pad->72
  int tid = threadIdx.x;
  int idx = blockIdx.x;
  int h = idx % NHEAD; idx /= NHEAD;
  int g = idx % NG;    idx /= NG;
  int b = idx;
  int wave = tid >> 6, lane = tid & 63;
  int l16 = lane & 15, l4 = lane >> 4;
  const int* sp = sort_idx + (size_t)b * NN + g * GS;
  int wy = g / 12, wx = g % 12;

  auto tokof = [&](int i) -> int {
    if constexpr (MODE == 0) {
      return sp[i];
    } else {
      int sy = (wy * 16 + (i >> 4) + 8) % 192;
      int sx = (wx * 16 + (i & 15) + 8) % 192;
      return sy * 192 + sx;
    }
  };

  // ---- stage K ([tok][ch]) and V transposed ([ch][tok]) ----
#pragma unroll
  for (int it = 0; it < 4; it++) {
    int li = tid + it * 256;             // 0..1023
    int tok = li >> 2, q8 = (li & 3) * 8;
    size_t bas = ((size_t)b * NN + tokof(tok)) * 576 + h * HD + q8;
    uint4 kv = *reinterpret_cast<const uint4*>(qkv + bas + CC);
    *reinterpret_cast<uint4*>(&Ks[tok][q8]) = kv;
    ushort4 v0 = *reinterpret_cast<const ushort4*>(qkv + bas + 2 * CC);
    ushort4 v1 = *reinterpret_cast<const ushort4*>(qkv + bas + 2 * CC + 4);
    Vt[q8 + 0][tok] = v0.x; Vt[q8 + 1][tok] = v0.y;
    Vt[q8 + 2][tok] = v0.z; Vt[q8 + 3][tok] = v0.w;
    Vt[q8 + 4][tok] = v1.x; Vt[q8 + 5][tok] = v1.y;
    Vt[q8 + 6][tok] = v1.z; Vt[q8 + 7][tok] = v1.w;
  }

  // ---- load Q fragments, fold scale into bf16 ----
  float qscale = (MODE == 0) ? __expf(fminf(lgsc[0], 4.605170185988092f))
                             : 0.17677669529663687f;
  short8 qf[4];
#pragma unroll
  for (int qt = 0; qt < 4; qt++) {
    int qrow = wave * 64 + qt * 16 + l16;
    size_t bas = ((size_t)b * NN + tokof(qrow)) * 576 + h * HD + l4 * 8;
    uint4 u = *reinterpret_cast<const uint4*>(qkv + bas);
    float f[8]; up8(u, f);
    short8 q;
#pragma unroll
    for (int j = 0; j < 8; j++) ((u16*)&q)[j] = f2b(f[j] * qscale);
    qf[qt] = q;
  }
  __syncthreads();

  bool bnd = (MODE == 1) && ((wy == 11) || (wx == 11));
  float m_r[4][4], l_r[4][4];
  f32x4 Oc[4][2];
#pragma unroll
  for (int qt = 0; qt < 4; qt++) {
#pragma unroll
    for (int r = 0; r < 4; r++) { m_r[qt][r] = -1e30f; l_r[qt][r] = 0.f; }
#pragma unroll
    for (int ct = 0; ct < 2; ct++) Oc[qt][ct] = (f32x4){0.f, 0.f, 0.f, 0.f};
  }

  for (int kc = 0; kc < 4; kc++) {
    // ---- S = (scaled Q) · K^T ----
    f32x4 S[4][4];
#pragma unroll
    for (int kt = 0; kt < 4; kt++) {
      int key = kc * 64 + kt * 16 + l16;
      short8 kf = *reinterpret_cast<const short8*>(&Ks[key][l4 * 8]);
#pragma unroll
      for (int qt = 0; qt < 4; qt++) {
        f32x4 z = (f32x4){0.f, 0.f, 0.f, 0.f};
        S[qt][kt] = __builtin_amdgcn_mfma_f32_16x16x32_bf16(qf[qt], kf, z, 0, 0, 0);
      }
    }
    // ---- bias (winmsa): rpb always, mask only for boundary windows ----
    if constexpr (MODE == 1) {
#pragma unroll
      for (int qt = 0; qt < 4; qt++)
#pragma unroll
        for (int kt = 0; kt < 4; kt++)
#pragma unroll
          for (int r = 0; r < 4; r++) {
            int q = wave * 64 + qt * 16 + 4 * l4 + r;
            int k = kc * 64 + kt * 16 + l16;
            float bias = rpbf[h * 65536 + q * 256 + k];
            if (bnd) bias += amask[(size_t)g * 65536 + q * 256 + k];
            S[qt][kt][r] += bias;
          }
    }
    // ---- online softmax (row = 4*l4 + r, 16-lane row groups) ----
#pragma unroll
    for (int qt = 0; qt < 4; qt++) {
#pragma unroll
      for (int r = 0; r < 4; r++) {
        float cm = fmaxf(fmaxf(S[qt][0][r], S[qt][1][r]), fmaxf(S[qt][2][r], S[qt][3][r]));
#pragma unroll
        for (int o = 1; o < 16; o <<= 1) cm = fmaxf(cm, __shfl_xor(cm, o));
        float mn = fmaxf(m_r[qt][r], cm);
        float corr = __expf(m_r[qt][r] - mn);
        m_r[qt][r] = mn;
        l_r[qt][r] *= corr;
        Oc[qt][0][r] *= corr;
        Oc[qt][1][r] *= corr;
        float psum = 0.f;
#pragma unroll
        for (int kt = 0; kt < 4; kt++) {
          float p = __expf(S[qt][kt][r] - mn);
          S[qt][kt][r] = p;
          psum += p;
        }
#pragma unroll
        for (int o = 1; o < 16; o <<= 1) psum += __shfl_xor(psum, o);
        l_r[qt][r] += psum;
      }
    }
    // ---- P -> per-wave LDS (C/D layout -> row-major) ----
#pragma unroll
    for (int qt = 0; qt < 4; qt++)
#pragma unroll
      for (int kt = 0; kt < 4; kt++)
#pragma unroll
        for (int r = 0; r < 4; r++)
          Ps[wave][qt * 16 + 4 * l4 + r][kt * 16 + l16] = f2b(S[qt][kt][r]);
    // ---- O += P · V ----
#pragma unroll
    for (int s = 0; s < 2; s++) {
      short8 pa[4];
#pragma unroll
      for (int qt = 0; qt < 4; qt++)
        pa[qt] = *reinterpret_cast<const short8*>(&Ps[wave][qt * 16 + l16][s * 32 + l4 * 8]);
#pragma unroll
      for (int ct = 0; ct < 2; ct++) {
        short8 vf = *reinterpret_cast<const short8*>(&Vt[ct * 16 + l16][kc * 64 + s * 32 + l4 * 8]);
#pragma unroll
        for (int qt = 0; qt < 4; qt++)
          Oc[qt][ct] = __builtin_amdgcn_mfma_f32_16x16x32_bf16(pa[qt], vf, Oc[qt][ct], 0, 0, 0);
      }
    }
  }

  // ---- epilogue: normalize, store bf16 ----
  const int coff = (MODE == 0) ? 0 : CC;
#pragma unroll
  for (int qt = 0; qt < 4; qt++) {
#pragma unroll
    for (int r = 0; r < 4; r++) {
      float inv = 1.f / l_r[qt][r];
      int tok = tokof(wave * 64 + qt * 16 + 4 * l4 + r);
      u16* ob = ao + ((size_t)b * NN + tok) * 384 + coff + h * HD;
      ob[l16]      = f2b(Oc[qt][0][r] * inv);
      ob[16 + l16] = f2b(Oc[qt][1][r] * inv);
    }
  }
}

// ---------------- concat proj weights / biases ----------------
__global__ void prep_kernel(const float* __restrict__ pa_w, const float* __restrict__ pw_w,
                            const float* __restrict__ pa_b, const float* __restrict__ pw_b,
                            float* __restrict__ wcat, float* __restrict__ bcat) {
  int i = blockIdx.x * 256 + threadIdx.x;  // 73728
  int k = i / 192, n = i % 192;
  wcat[i] = (k < 192) ? pa_w[k * 192 + n] : pw_w[(k - 192) * 192 + n];
  if (i < 192) bcat[i] = pa_b[i] + pw_b[i];
}

// ---------------- depthwise 5x5 conv + gelu + residual (bf16 in/out) ----------------
__global__ __launch_bounds__(384) void dwconv_kernel(const u16* __restrict__ y2,
                                                     const float* __restrict__ dww,
                                                     const float* __restrict__ dwb,
                                                     u16* __restrict__ y2pc) {
  int c = threadIdx.x;
  int p = blockIdx.x;
  int x = p % WW;
  int y = (p / WW) % HH;
  int b = p / (HH * WW);
  const float* w = dww + c * 25;
  float a = 0.f;
#pragma unroll
  for (int dy = 0; dy < 5; dy++) {
    int yy = y + dy - 2;
    if (yy < 0 || yy >= HH) continue;
#pragma unroll
    for (int dx = 0; dx < 5; dx++) {
      int xx = x + dx - 2;
      if (xx < 0 || xx >= WW) continue;
      a += b2f(y2[((size_t)b * NN + yy * WW + xx) * HID + c]) * w[dy * 5 + dx];
    }
  }
  float gl = gelu_f(a + dwb[c]);
  size_t o = ((size_t)b * NN + y * WW + x) * HID + c;
  y2pc[o] = f2b(b2f(y2[o]) + gl);
}

// ---------------- td refinement ----------------
__global__ __launch_bounds__(256) void zsum_kernel(const float* __restrict__ sim,
                                                   float* __restrict__ Z) {
  int blk = blockIdx.x;
  int b = blk / NG;
  int n0 = (blk % NG) * 256;
  int tid = threadIdx.x, m = tid & 63, sub = tid >> 6;
  float a = 0.f;
  const float* sp = sim + ((size_t)b * NN + n0) * MM;
  for (int n = sub; n < 256; n += 4) a += __expf(sp[n * MM + m]);
  __shared__ float red[4][64];
  red[sub][m] = a;
  __syncthreads();
  if (tid < 64) atomicAdd(&Z[b * MM + m], red[0][m] + red[1][m] + red[2][m] + red[3][m]);
}

__global__ void invz_kernel(const float* __restrict__ Z, float* __restrict__ invZ) {
  int i = threadIdx.x;  // 128
  invZ[i] = 1.f / Z[i];
}

__global__ __launch_bounds__(192, 2) void tdacc_kernel(const float* __restrict__ sim,
                                                       const float* __restrict__ invZ,
                                                       const u16* __restrict__ ln3x,
                                                       float* __restrict__ tdacc) {
  __shared__ u16 w_s[256][64];  // 32 KB
  int blk = blockIdx.x;
  int b = blk / NG;
  int n0 = (blk % NG) * 256;
  int tid = threadIdx.x;
  const float* sp = sim + ((size_t)b * NN + n0) * MM;
  const float* iz = invZ + b * MM;
  for (int i = tid; i < 256 * 64; i += 192)
    w_s[i >> 6][i & 63] = f2b(__expf(sp[i]) * iz[i & 63]);
  __syncthreads();
  float acc[64];
#pragma unroll
  for (int m = 0; m < 64; m++) acc[m] = 0.f;
  const u16* lp = ln3x + ((size_t)b * NN + n0) * CC + tid;
  for (int n = 0; n < 256; n++) {
    float val = b2f(lp[(size_t)n * CC]);
    const uint4* wr = reinterpret_cast<const uint4*>(&w_s[n][0]);
#pragma unroll
    for (int c8 = 0; c8 < 8; c8++) {
      float f[8]; up8(wr[c8], f);
#pragma unroll
      for (int t = 0; t < 8; t++) acc[c8 * 8 + t] += f[t] * val;
    }
  }
  for (int m = 0; m < 64; m++) atomicAdd(&tdacc[((size_t)b * MM + m) * CC + tid], acc[m]);
}

__global__ void tdfin_kernel(const float* __restrict__ td, const float* __restrict__ sigma,
                             const float* __restrict__ tdacc, float* __restrict__ out) {
  int i = blockIdx.x * 256 + threadIdx.x;  // 24576
  if (i >= BB * MM * CC) return;
  int m = (i / CC) % MM;
  float s = 1.f / (1.f + __expf(-sigma[m]));
  out[i] = s * td[i] + (1.f - s) * tdacc[i];
}

// ---------------- workspace layout (bytes) ----------------
static constexpr size_t oQKV = 0;                                   // u16 BN*576 (later y2 bf16)
static constexpr size_t oXN  = oQKV + (size_t)BN * 576 * 2;         // u16 BN*192 (xn1/xn2/ln3x)
static constexpr size_t oAO  = oXN  + (size_t)BN * CC * 2;          // u16 BN*384 (aca|win; later y2pc)
static constexpr size_t oSIM = oAO  + (size_t)BN * 384 * 2;         // f32 BN*64
static constexpr size_t oQN  = oSIM + (size_t)BN * MM * 4;          // f32 BN*10
static constexpr size_t oRPB = oQN  + (size_t)BN * RC * 4;          // f32 6*65536
static constexpr size_t oVTD = oRPB + (size_t)6 * 65536 * 4;        // f32 BB*MM*CC
static constexpr size_t oKNV = oVTD + (size_t)BB * MM * CC * 4;     // f32 BB*MM*RC
static constexpr size_t oWC  = oKNV + (size_t)BB * MM * RC * 4;     // f32 384*192
static constexpr size_t oBC  = oWC  + (size_t)384 * 192 * 4;        // f32 192 (pad to 1024)
static constexpr size_t oTK  = oBC  + 1024;                         // int BN
static constexpr size_t oSORT= oTK  + (size_t)BN * 4;               // int BN
static constexpr size_t oHIST= oSORT+ (size_t)BN * 4;               // int 128   } contiguous,
static constexpr size_t oBASE= oHIST+ 512;                          // int 128   } zeroed by
static constexpr size_t oZ   = oBASE+ 512;                          // f32 128   } zero_kernel
static constexpr size_t oTDA = oZ   + 512;                          // f32 BB*MM*CC }
static constexpr size_t oINV = oTDA + (size_t)BB * MM * CC * 4;     // f32 128
static constexpr size_t WS_NEEDED = oINV + 512;                     // ~194.4 MB

extern "C" void kernel_launch(void* const* d_in, const int* in_sizes, int n_in,
                              void* d_out, int out_size, void* d_ws, size_t ws_size,
                              hipStream_t stream) {
  if (ws_size < WS_NEEDED) return;  // diagnostic tripwire
  const float* x       = (const float*)d_in[0];
  const float* td      = (const float*)d_in[1];
  const int*   rpi     = (const int*)d_in[2];
  const float* amask   = (const float*)d_in[3];
  const float* n1g     = (const float*)d_in[6];
  const float* n1b     = (const float*)d_in[7];
  const float* n2g     = (const float*)d_in[8];
  const float* n2b     = (const float*)d_in[9];
  const float* n3g     = (const float*)d_in[10];
  const float* n3b     = (const float*)d_in[11];
  const float* wqkv_w  = (const float*)d_in[12];
  const float* wqkv_b  = (const float*)d_in[13];
  const float* wq_w    = (const float*)d_in[14];
  const float* wq_b    = (const float*)d_in[15];
  const float* wk_w    = (const float*)d_in[16];
  const float* wk_b    = (const float*)d_in[17];
  const float* wv_w    = (const float*)d_in[18];
  const float* wv_b    = (const float*)d_in[19];
  const float* atd_sc  = (const float*)d_in[20];
  const float* paca_w  = (const float*)d_in[21];
  const float* paca_b  = (const float*)d_in[22];
  const float* lgsc    = (const float*)d_in[23];
  const float* rpb_tab = (const float*)d_in[24];
  const float* pwin_w  = (const float*)d_in[25];
  const float* pwin_b  = (const float*)d_in[26];
  const float* fc1_w   = (const float*)d_in[27];
  const float* fc1_b   = (const float*)d_in[28];
  const float* dw_w    = (const float*)d_in[29];
  const float* dw_b    = (const float*)d_in[30];
  const float* fc2_w   = (const float*)d_in[31];
  const float* fc2_b   = (const float*)d_in[32];
  const float* sigma   = (const float*)d_in[33];
  float* out = (float*)d_out;
  char* wsb = (char*)d_ws;

  u16*   QKVb = (u16*)(wsb + oQKV);
  u16*   XNb  = (u16*)(wsb + oXN);
  u16*   AOb  = (u16*)(wsb + oAO);
  float* SIM  = (float*)(wsb + oSIM);
  float* QN   = (float*)(wsb + oQN);
  float* RPB  = (float*)(wsb + oRPB);
  float* VTD  = (float*)(wsb + oVTD);
  float* KNV  = (float*)(wsb + oKNV);
  float* WC   = (float*)(wsb + oWC);
  float* BC   = (float*)(wsb + oBC);
  int*   TK   = (int*)(wsb + oTK);
  int*   SORT = (int*)(wsb + oSORT);
  int*   HIST = (int*)(wsb + oHIST);
  int*   BASE = (int*)(wsb + oBASE);
  float* Z    = (float*)(wsb + oZ);
  float* TDA  = (float*)(wsb + oTDA);
  float* INVZ = (float*)(wsb + oINV);

  zero_kernel<<<98, 256, 0, stream>>>(HIST, 24960);  // hist+base+Z+tdacc
  ln1_kernel<<<BN / 4, 256, 0, stream>>>(x, n1g, n1b, wq_w, wq_b, XNb, QN);
  tdproj_kernel<<<BB, 1024, 0, stream>>>(td, wk_w, wk_b, wv_w, wv_b, atd_sc, KNV, VTD);
  gemm_bf<0><<<dim3(BN / 128, 9), 256, 0, stream>>>(XNb, wqkv_w, wqkv_b, QKVb, 192, 576);
  atd_kernel<<<BN / 64, 256, 0, stream>>>(QN, x, KNV, VTD, SIM, TK, out);
  hist_kernel<<<BN / 256, 256, 0, stream>>>(TK, HIST);
  scan_kernel<<<1, 128, 0, stream>>>(HIST, BASE);
  scatter_kernel<<<BB * MM, 256, 0, stream>>>(TK, BASE, SORT);
  rpb_kernel<<<256, 256, 0, stream>>>(rpi, rpb_tab, RPB);
  attn_mfma_kernel<0><<<BB * NG * NHEAD, 256, 0, stream>>>(QKVb, SORT, lgsc, RPB, amask, AOb);
  attn_mfma_kernel<1><<<BB * NG * NHEAD, 256, 0, stream>>>(QKVb, SORT, lgsc, RPB, amask, AOb);
  prep_kernel<<<288, 256, 0, stream>>>(paca_w, pwin_w, paca_b, pwin_b, WC, BC);
  gemm_bf<2><<<dim3(BN / 128, 3), 256, 0, stream>>>(AOb, WC, BC, out, 384, 192);
  ln_kernel<<<BN / 4, 256, 0, stream>>>(out, XNb, n2g, n2b);
  gemm_bf<1><<<dim3(BN / 128, 6), 256, 0, stream>>>(XNb, fc1_w, fc1_b, QKVb, 192, 384);
  dwconv_kernel<<<BB * HH * WW, 384, 0, stream>>>(QKVb, dw_w, dw_b, AOb);
  gemm_bf<2><<<dim3(BN / 128, 3), 256, 0, stream>>>(AOb, fc2_w, fc2_b, out, 384, 192);
  ln_kernel<<<BN / 4, 256, 0, stream>>>(out, XNb, n3g, n3b);
  zsum_kernel<<<BB * NG, 256, 0, stream>>>(SIM, Z);
  invz_kernel<<<1, 128, 0, stream>>>(Z, INVZ);
  tdacc_kernel<<<BB * NG, 192, 0, stream>>>(SIM, INVZ, XNb, TDA);
  tdfin_kernel<<<96, 256, 0, stream>>>(td, sigma, TDA, out + (size_t)BN * CC);
}

// Round 7
// 1702.036 us; speedup vs baseline: 3.5568x; 1.6142x over previous
//
#include <hip/hip_runtime.h>
#include <math.h>

// ---------------- problem constants ----------------
#define BB 2
#define HH 192
#define WW 192
#define NN 36864
#define CC 192
#define NHEAD 6
#define HD 32
#define MM 64
#define RC 10
#define GS 256
#define NG 144
#define HID 384
#define BN 73728

typedef unsigned short u16;
typedef __attribute__((ext_vector_type(8))) short short8;
typedef __attribute__((ext_vector_type(4))) float f32x4;

__device__ __forceinline__ float b2f(u16 u) { return __uint_as_float(((unsigned)u) << 16); }
__device__ __forceinline__ u16 f2b(float f) {
  unsigned v = __float_as_uint(f);
  return (u16)((v + 0x7fffu + ((v >> 16) & 1u)) >> 16);
}
__device__ __forceinline__ void up8(uint4 u, float* f) {
  f[0] = __uint_as_float(u.x << 16); f[1] = __uint_as_float(u.x & 0xffff0000u);
  f[2] = __uint_as_float(u.y << 16); f[3] = __uint_as_float(u.y & 0xffff0000u);
  f[4] = __uint_as_float(u.z << 16); f[5] = __uint_as_float(u.z & 0xffff0000u);
  f[6] = __uint_as_float(u.w << 16); f[7] = __uint_as_float(u.w & 0xffff0000u);
}
__device__ __forceinline__ float gelu_f(float v) {
  return 0.5f * v * (1.f + erff(v * 0.70710678118654752f));
}

// ---------------- zero scratch ----------------
__global__ void zero_kernel(int* __restrict__ p, int n) {
  int i = blockIdx.x * 256 + threadIdx.x;
  if (i < n) p[i] = 0;
}

// ---------------- LN1 fused with ATD q projection (fp32 path) ----------------
__global__ __launch_bounds__(256) void ln1_kernel(const float* __restrict__ x,
                                                  const float* __restrict__ g,
                                                  const float* __restrict__ be,
                                                  const float* __restrict__ wq,
                                                  const float* __restrict__ wqb,
                                                  u16* __restrict__ xnb,
                                                  float* __restrict__ qn) {
  int row = blockIdx.x * 4 + (threadIdx.x >> 6);
  int lane = threadIdx.x & 63;
  const float* p = x + (size_t)row * CC;
  float v0 = p[lane], v1 = p[lane + 64], v2 = p[lane + 128];
  float s = v0 + v1 + v2;
#pragma unroll
  for (int o = 32; o > 0; o >>= 1) s += __shfl_xor(s, o);
  float mu = s * (1.f / 192.f);
  float d0 = v0 - mu, d1 = v1 - mu, d2 = v2 - mu;
  float q2 = d0 * d0 + d1 * d1 + d2 * d2;
#pragma unroll
  for (int o = 32; o > 0; o >>= 1) q2 += __shfl_xor(q2, o);
  float rstd = rsqrtf(q2 * (1.f / 192.f) + 1e-5f);
  float xn0 = d0 * rstd * g[lane] + be[lane];
  float xn1 = d1 * rstd * g[lane + 64] + be[lane + 64];
  float xn2 = d2 * rstd * g[lane + 128] + be[lane + 128];
  u16* op = xnb + (size_t)row * CC;
  op[lane] = f2b(xn0); op[lane + 64] = f2b(xn1); op[lane + 128] = f2b(xn2);
  float qv[RC];
#pragma unroll
  for (int r = 0; r < RC; r++) {
    float t = xn0 * wq[lane * RC + r] + xn1 * wq[(lane + 64) * RC + r] + xn2 * wq[(lane + 128) * RC + r];
#pragma unroll
    for (int o = 32; o > 0; o >>= 1) t += __shfl_xor(t, o);
    qv[r] = t + wqb[r];
  }
  float nr = 0.f;
#pragma unroll
  for (int r = 0; r < RC; r++) nr += qv[r] * qv[r];
  float inv = 1.f / fmaxf(sqrtf(nr), 1e-12f);
  if (lane == 0) {
    float* qo = qn + (size_t)row * RC;
#pragma unroll
    for (int r = 0; r < RC; r++) qo[r] = qv[r] * inv;
  }
}

// ---------------- generic LN -> bf16 out ----------------
__global__ __launch_bounds__(256) void ln_kernel(const float* __restrict__ in,
                                                 u16* __restrict__ out,
                                                 const float* __restrict__ g,
                                                 const float* __restrict__ be) {
  int row = blockIdx.x * 4 + (threadIdx.x >> 6);
  int lane = threadIdx.x & 63;
  const float* p = in + (size_t)row * CC;
  float v0 = p[lane], v1 = p[lane + 64], v2 = p[lane + 128];
  float s = v0 + v1 + v2;
#pragma unroll
  for (int o = 32; o > 0; o >>= 1) s += __shfl_xor(s, o);
  float mu = s * (1.f / 192.f);
  float d0 = v0 - mu, d1 = v1 - mu, d2 = v2 - mu;
  float q2 = d0 * d0 + d1 * d1 + d2 * d2;
#pragma unroll
  for (int o = 32; o > 0; o >>= 1) q2 += __shfl_xor(q2, o);
  float rstd = rsqrtf(q2 * (1.f / 192.f) + 1e-5f);
  u16* op = out + (size_t)row * CC;
  op[lane]       = f2b(d0 * rstd * g[lane] + be[lane]);
  op[lane + 64]  = f2b(d1 * rstd * g[lane + 64] + be[lane + 64]);
  op[lane + 128] = f2b(d2 * rstd * g[lane + 128] + be[lane + 128]);
}

// ---------------- GEMM: A bf16 (row-major, lda=K), B f32 (ldb=Nn) ----------------
// EPI: 0 = store bf16 ; 1 = gelu + store bf16 ; 2 = f32 RMW add
template <int EPI>
__global__ __launch_bounds__(256) void gemm_bf(const u16* __restrict__ A,
                                               const float* __restrict__ Bw,
                                               const float* __restrict__ bias,
                                               void* __restrict__ Cv,
                                               int K, int Nn) {
  __shared__ float As[32][132];
  __shared__ float Bs[32][64];
  int tid = threadIdx.x;
  int m0 = blockIdx.x * 128, n0 = blockIdx.y * 64;
  float acc[8][4];
#pragma unroll
  for (int i = 0; i < 8; i++)
#pragma unroll
    for (int j = 0; j < 4; j++) acc[i][j] = 0.f;
  int arow = tid >> 1, akh = (tid & 1) * 16;
  int br = tid >> 4, bc4 = tid & 15;
  int ty = tid >> 4, tx = tid & 15;
  for (int k0 = 0; k0 < K; k0 += 32) {
    const uint4* ap = reinterpret_cast<const uint4*>(A + (size_t)(m0 + arow) * K + k0 + akh);
    uint4 a0 = ap[0], a1 = ap[1];
    float f[16];
    up8(a0, f); up8(a1, f + 8);
#pragma unroll
    for (int j = 0; j < 16; j++) As[akh + j][arow] = f[j];
#pragma unroll
    for (int i = 0; i < 2; i++) {
      float4 bv = *reinterpret_cast<const float4*>(Bw + (size_t)(k0 + br + 16 * i) * Nn + n0 + bc4 * 4);
      *reinterpret_cast<float4*>(&Bs[br + 16 * i][bc4 * 4]) = bv;
    }
    __syncthreads();
#pragma unroll
    for (int kk = 0; kk < 32; kk++) {
      float4 b4 = *reinterpret_cast<const float4*>(&Bs[kk][tx * 4]);
      float4 aA = *reinterpret_cast<const float4*>(&As[kk][ty * 8]);
      float4 aB = *reinterpret_cast<const float4*>(&As[kk][ty * 8 + 4]);
      acc[0][0] += aA.x * b4.x; acc[0][1] += aA.x * b4.y; acc[0][2] += aA.x * b4.z; acc[0][3] += aA.x * b4.w;
      acc[1][0] += aA.y * b4.x; acc[1][1] += aA.y * b4.y; acc[1][2] += aA.y * b4.z; acc[1][3] += aA.y * b4.w;
      acc[2][0] += aA.z * b4.x; acc[2][1] += aA.z * b4.y; acc[2][2] += aA.z * b4.z; acc[2][3] += aA.z * b4.w;
      acc[3][0] += aA.w * b4.x; acc[3][1] += aA.w * b4.y; acc[3][2] += aA.w * b4.z; acc[3][3] += aA.w * b4.w;
      acc[4][0] += aB.x * b4.x; acc[4][1] += aB.x * b4.y; acc[4][2] += aB.x * b4.z; acc[4][3] += aB.x * b4.w;
      acc[5][0] += aB.y * b4.x; acc[5][1] += aB.y * b4.y; acc[5][2] += aB.y * b4.z; acc[5][3] += aB.y * b4.w;
      acc[6][0] += aB.z * b4.x; acc[6][1] += aB.z * b4.y; acc[6][2] += aB.z * b4.z; acc[6][3] += aB.z * b4.w;
      acc[7][0] += aB.w * b4.x; acc[7][1] += aB.w * b4.y; acc[7][2] += aB.w * b4.z; acc[7][3] += aB.w * b4.w;
    }
    __syncthreads();
  }
  float4 bv = *reinterpret_cast<const float4*>(bias + n0 + tx * 4);
#pragma unroll
  for (int i = 0; i < 8; i++) {
    size_t off = (size_t)(m0 + ty * 8 + i) * Nn + n0 + tx * 4;
    float c0 = acc[i][0] + bv.x, c1 = acc[i][1] + bv.y, c2 = acc[i][2] + bv.z, c3 = acc[i][3] + bv.w;
    if constexpr (EPI == 2) {
      float* C = (float*)Cv;
      float4 o = *reinterpret_cast<float4*>(C + off);
      o.x += c0; o.y += c1; o.z += c2; o.w += c3;
      *reinterpret_cast<float4*>(C + off) = o;
    } else {
      if constexpr (EPI == 1) { c0 = gelu_f(c0); c1 = gelu_f(c1); c2 = gelu_f(c2); c3 = gelu_f(c3); }
      u16* C = (u16*)Cv;
      ushort4 sv;
      sv.x = f2b(c0); sv.y = f2b(c1); sv.z = f2b(c2); sv.w = f2b(c3);
      *reinterpret_cast<ushort4*>(C + off) = sv;
    }
  }
}

// ---------------- token-dictionary k/v projections (fp32, tiny) ----------------
__global__ __launch_bounds__(1024) void tdproj_kernel(const float* __restrict__ td,
                                                      const float* __restrict__ wk,
                                                      const float* __restrict__ wkb,
                                                      const float* __restrict__ wv,
                                                      const float* __restrict__ wvb,
                                                      const float* __restrict__ atd_scale,
                                                      float* __restrict__ knv,
                                                      float* __restrict__ vtd) {
  int b = blockIdx.x, tid = threadIdx.x;
  __shared__ float td_s[MM * CC];   // 48 KB
  __shared__ float k_s[MM][RC];
  const float* tdb = td + (size_t)b * MM * CC;
  for (int i = tid; i < MM * CC; i += 1024) td_s[i] = tdb[i];
  __syncthreads();
  for (int i = tid; i < MM * CC; i += 1024) {
    int m = i / CC, c = i % CC;
    float a = wvb[c];
    for (int r = 0; r < CC; r++) a += td_s[m * CC + r] * wv[r * CC + c];
    vtd[(size_t)b * MM * CC + i] = a;
  }
  for (int i = tid; i < MM * RC; i += 1024) {
    int m = i / RC, r = i % RC;
    float a = wkb[r];
    for (int c = 0; c < CC; c++) a += td_s[m * CC + c] * wk[c * RC + r];
    k_s[m][r] = a;
  }
  __syncthreads();
  if (tid < MM) {
    int m = tid;
    float nr = 0.f;
    for (int r = 0; r < RC; r++) nr += k_s[m][r] * k_s[m][r];
    float inv = 1.f / fmaxf(sqrtf(nr), 1e-12f);
    float sc = 1.f + fminf(fmaxf(atd_scale[m], 0.f), 1.f) * 4.1588830833596715f; // ln(64)
    for (int r = 0; r < RC; r++) knv[(size_t)b * MM * RC + m * RC + r] = k_s[m][r] * inv * sc;
  }
}

// ---------------- ATD cross attention (fp32): sim, tk_id, xacc = x + x_atd ----------------
__global__ __launch_bounds__(256, 2) void atd_kernel(const float* __restrict__ qn,
                                                     const float* __restrict__ x,
                                                     const float* __restrict__ knv,
                                                     const float* __restrict__ vtd,
                                                     float* __restrict__ sim,
                                                     int* __restrict__ tkid,
                                                     float* __restrict__ xacc) {
  __shared__ float v_s[MM][CC];   // 48 KB
  __shared__ float kn_s[MM][11];
  __shared__ float p_s[4][64];
  int tid = threadIdx.x;
  int b = (blockIdx.x * 64) / NN;
  float* vflat = &v_s[0][0];
  for (int i = tid; i < MM * CC; i += 256) vflat[i] = vtd[(size_t)b * MM * CC + i];
  for (int i = tid; i < MM * RC; i += 256) kn_s[i / RC][i % RC] = knv[(size_t)b * MM * RC + i];
  __syncthreads();
  int wave = tid >> 6, lane = tid & 63;
  for (int it = 0; it < 16; it++) {
    int tg = blockIdx.x * 64 + it * 4 + wave;
    const float* qr = qn + (size_t)tg * RC;
    float s = 0.f;
#pragma unroll
    for (int r = 0; r < RC; r++) s += qr[r] * kn_s[lane][r];
    float mx = s; int ai = lane;
#pragma unroll
    for (int o = 32; o > 0; o >>= 1) {
      float ov = __shfl_xor(mx, o); int oi = __shfl_xor(ai, o);
      if (ov > mx || (ov == mx && oi < ai)) { mx = ov; ai = oi; }
    }
    float e = __expf(s - mx);
    float sum = e;
#pragma unroll
    for (int o = 32; o > 0; o >>= 1) sum += __shfl_xor(sum, o);
    float p = e / sum;
    sim[(size_t)tg * MM + lane] = p;
    if (lane == 0) tkid[tg] = ai;
    p_s[wave][lane] = p;
    float a0 = 0.f, a1 = 0.f, a2 = 0.f;
#pragma unroll
    for (int m = 0; m < MM; m++) {
      float pm = p_s[wave][m];
      a0 += pm * v_s[m][lane];
      a1 += pm * v_s[m][lane + 64];
      a2 += pm * v_s[m][lane + 128];
    }
    const float* xr = x + (size_t)tg * CC;
    float* xo = xacc + (size_t)tg * CC;
    xo[lane]       = xr[lane]       + a0;
    xo[lane + 64]  = xr[lane + 64]  + a1;
    xo[lane + 128] = xr[lane + 128] + a2;
  }
}

// ---------------- stable counting sort of tk_id ----------------
__global__ void hist_kernel(const int* __restrict__ tkid, int* __restrict__ hist) {
  int i = blockIdx.x * 256 + threadIdx.x;
  if (i < BN) atomicAdd(&hist[(i / NN) * MM + tkid[i]], 1);
}

__global__ void scan_kernel(const int* __restrict__ hist, int* __restrict__ base) {
  int lane = threadIdx.x & 63, b = threadIdx.x >> 6;  // 128 threads
  int v = hist[b * MM + lane];
  int xx = v;
#pragma unroll
  for (int o = 1; o < 64; o <<= 1) { int t = __shfl_up(xx, o); if (lane >= o) xx += t; }
  base[b * MM + lane] = xx - v;
}

__global__ __launch_bounds__(256) void scatter_kernel(const int* __restrict__ tkid,
                                                      const int* __restrict__ base,
                                                      int* __restrict__ sort_idx) {
  int bk = blockIdx.x;
  int b = bk >> 6, key = bk & 63;
  int tid = threadIdx.x, wave = tid >> 6, lane = tid & 63;
  __shared__ int wtot[4];
  int offset = base[b * MM + key];
  const int* tk = tkid + (size_t)b * NN;
  for (int c0 = 0; c0 < NN; c0 += 256) {
    int i = c0 + tid;
    bool f = (tk[i] == key);
    unsigned long long mb = __ballot(f);
    int wpre = __popcll(mb & ((1ull << lane) - 1ull));
    if (lane == 0) wtot[wave] = __popcll(mb);
    __syncthreads();
    int pre = wpre;
#pragma unroll
    for (int w = 0; w < 4; w++) if (w < wave) pre += wtot[w];
    int tot = wtot[0] + wtot[1] + wtot[2] + wtot[3];
    if (f) sort_idx[(size_t)b * NN + offset + pre] = i;
    offset += tot;
    __syncthreads();
  }
}

// ---------------- rpb gather ----------------
__global__ void rpb_kernel(const int* __restrict__ rpi, const float* __restrict__ table,
                           float* __restrict__ rpbf) {
  int ij = blockIdx.x * 256 + threadIdx.x;  // 65536
  int idx = rpi[ij];
#pragma unroll
  for (int h = 0; h < NHEAD; h++) rpbf[h * 65536 + ij] = table[idx * NHEAD + h];
}

// ---------------- MFMA attention (shared by AC_MSA and window MSA) ----------------
// MODE 0 = acmsa (sorted-token groups, logit_scale), MODE 1 = winmsa (rpb + mask)
template <int MODE>
__global__ __launch_bounds__(256, 2) void attn_mfma_kernel(const u16* __restrict__ qkv,
                                                           const int* __restrict__ sort_idx,
                                                           const float* __restrict__ lgsc,
                                                           const float* __restrict__ rpbf,
                                                           const float* __restrict__ amask,
                                                           u16* __restrict__ ao) {
  __shared__ u16 Ks[GS][40];       // [token][ch] pad->40 (2-way conflict = free)
  __shared__ u16 Vt[HD][GS + 8];   // [ch][token] transposed, pad->264
  __shared__ u16 Ps[4][64][72];    // per-wave P round-trip, pad->72
  int tid = threadIdx.x;
  int idx = blockIdx.x;
  int h = idx % NHEAD; idx /= NHEAD;
  int g = idx % NG;    idx /= NG;
  int b = idx;
  int wave = tid >> 6, lane = tid & 63;
  int l16 = lane & 15, l4 = lane >> 4;
  const int* sp = sort_idx + (size_t)b * NN + g * GS;
  int wy = g / 12, wx = g % 12;

  auto tokof = [&](int i) -> int {
    if constexpr (MODE == 0) {
      return sp[i];
    } else {
      int sy = (wy * 16 + (i >> 4) + 8) % 192;
      int sx = (wx * 16 + (i & 15) + 8) % 192;
      return sy * 192 + sx;
    }
  };

  // ---- stage K ([tok][ch]) and V transposed ([ch][tok]) ----
#pragma unroll
  for (int it = 0; it < 4; it++) {
    int li = tid + it * 256;             // 0..1023
    int tok = li >> 2, q8 = (li & 3) * 8;
    size_t bas = ((size_t)b * NN + tokof(tok)) * 576 + h * HD + q8;
    uint4 kv = *reinterpret_cast<const uint4*>(qkv + bas + CC);
    *reinterpret_cast<uint4*>(&Ks[tok][q8]) = kv;
    ushort4 v0 = *reinterpret_cast<const ushort4*>(qkv + bas + 2 * CC);
    ushort4 v1 = *reinterpret_cast<const ushort4*>(qkv + bas + 2 * CC + 4);
    Vt[q8 + 0][tok] = v0.x; Vt[q8 + 1][tok] = v0.y;
    Vt[q8 + 2][tok] = v0.z; Vt[q8 + 3][tok] = v0.w;
    Vt[q8 + 4][tok] = v1.x; Vt[q8 + 5][tok] = v1.y;
    Vt[q8 + 6][tok] = v1.z; Vt[q8 + 7][tok] = v1.w;
  }

  // ---- load Q fragments, fold scale into bf16 ----
  float qscale = (MODE == 0) ? __expf(fminf(lgsc[0], 4.605170185988092f))
                             : 0.17677669529663687f;
  short8 qf[4];
#pragma unroll
  for (int qt = 0; qt < 4; qt++) {
    int qrow = wave * 64 + qt * 16 + l16;
    size_t bas = ((size_t)b * NN + tokof(qrow)) * 576 + h * HD + l4 * 8;
    uint4 u = *reinterpret_cast<const uint4*>(qkv + bas);
    float f[8]; up8(u, f);
    short8 q;
#pragma unroll
    for (int j = 0; j < 8; j++) ((u16*)&q)[j] = f2b(f[j] * qscale);
    qf[qt] = q;
  }
  __syncthreads();

  bool bnd = (MODE == 1) && ((wy == 11) || (wx == 11));
  float m_r[4][4], l_r[4][4];
  f32x4 Oc[4][2];
#pragma unroll
  for (int qt = 0; qt < 4; qt++) {
#pragma unroll
    for (int r = 0; r < 4; r++) { m_r[qt][r] = -1e30f; l_r[qt][r] = 0.f; }
#pragma unroll
    for (int ct = 0; ct < 2; ct++) Oc[qt][ct] = (f32x4){0.f, 0.f, 0.f, 0.f};
  }

  for (int kc = 0; kc < 4; kc++) {
    // ---- S = (scaled Q) · K^T ----
    f32x4 S[4][4];
#pragma unroll
    for (int kt = 0; kt < 4; kt++) {
      int key = kc * 64 + kt * 16 + l16;
      short8 kf = *reinterpret_cast<const short8*>(&Ks[key][l4 * 8]);
#pragma unroll
      for (int qt = 0; qt < 4; qt++) {
        f32x4 z = (f32x4){0.f, 0.f, 0.f, 0.f};
        S[qt][kt] = __builtin_amdgcn_mfma_f32_16x16x32_bf16(qf[qt], kf, z, 0, 0, 0);
      }
    }
    // ---- bias (winmsa): rpb always, mask only for boundary windows ----
    if constexpr (MODE == 1) {
#pragma unroll
      for (int qt = 0; qt < 4; qt++)
#pragma unroll
        for (int kt = 0; kt < 4; kt++)
#pragma unroll
          for (int r = 0; r < 4; r++) {
            int q = wave * 64 + qt * 16 + 4 * l4 + r;
            int k = kc * 64 + kt * 16 + l16;
            float bias = rpbf[h * 65536 + q * 256 + k];
            if (bnd) bias += amask[(size_t)g * 65536 + q * 256 + k];
            S[qt][kt][r] += bias;
          }
    }
    // ---- online softmax (row = 4*l4 + r, 16-lane row groups) ----
#pragma unroll
    for (int qt = 0; qt < 4; qt++) {
#pragma unroll
      for (int r = 0; r < 4; r++) {
        float cm = fmaxf(fmaxf(S[qt][0][r], S[qt][1][r]), fmaxf(S[qt][2][r], S[qt][3][r]));
#pragma unroll
        for (int o = 1; o < 16; o <<= 1) cm = fmaxf(cm, __shfl_xor(cm, o));
        float mn = fmaxf(m_r[qt][r], cm);
        float corr = __expf(m_r[qt][r] - mn);
        m_r[qt][r] = mn;
        l_r[qt][r] *= corr;
        Oc[qt][0][r] *= corr;
        Oc[qt][1][r] *= corr;
        float psum = 0.f;
#pragma unroll
        for (int kt = 0; kt < 4; kt++) {
          float p = __expf(S[qt][kt][r] - mn);
          S[qt][kt][r] = p;
          psum += p;
        }
#pragma unroll
        for (int o = 1; o < 16; o <<= 1) psum += __shfl_xor(psum, o);
        l_r[qt][r] += psum;
      }
    }
    // ---- P -> per-wave LDS (C/D layout -> row-major) ----
#pragma unroll
    for (int qt = 0; qt < 4; qt++)
#pragma unroll
      for (int kt = 0; kt < 4; kt++)
#pragma unroll
        for (int r = 0; r < 4; r++)
          Ps[wave][qt * 16 + 4 * l4 + r][kt * 16 + l16] = f2b(S[qt][kt][r]);
    // ---- O += P · V ----
#pragma unroll
    for (int s = 0; s < 2; s++) {
      short8 pa[4];
#pragma unroll
      for (int qt = 0; qt < 4; qt++)
        pa[qt] = *reinterpret_cast<const short8*>(&Ps[wave][qt * 16 + l16][s * 32 + l4 * 8]);
#pragma unroll
      for (int ct = 0; ct < 2; ct++) {
        short8 vf = *reinterpret_cast<const short8*>(&Vt[ct * 16 + l16][kc * 64 + s * 32 + l4 * 8]);
#pragma unroll
        for (int qt = 0; qt < 4; qt++)
          Oc[qt][ct] = __builtin_amdgcn_mfma_f32_16x16x32_bf16(pa[qt], vf, Oc[qt][ct], 0, 0, 0);
      }
    }
  }

  // ---- epilogue: normalize, store bf16 ----
  const int coff = (MODE == 0) ? 0 : CC;
#pragma unroll
  for (int qt = 0; qt < 4; qt++) {
#pragma unroll
    for (int r = 0; r < 4; r++) {
      float inv = 1.f / l_r[qt][r];
      int tok = tokof(wave * 64 + qt * 16 + 4 * l4 + r);
      u16* ob = ao + ((size_t)b * NN + tok) * 384 + coff + h * HD;
      ob[l16]      = f2b(Oc[qt][0][r] * inv);
      ob[16 + l16] = f2b(Oc[qt][1][r] * inv);
    }
  }
}

// ---------------- concat proj weights / biases ----------------
__global__ void prep_kernel(const float* __restrict__ pa_w, const float* __restrict__ pw_w,
                            const float* __restrict__ pa_b, const float* __restrict__ pw_b,
                            float* __restrict__ wcat, float* __restrict__ bcat) {
  int i = blockIdx.x * 256 + threadIdx.x;  // 73728
  int k = i / 192, n = i % 192;
  wcat[i] = (k < 192) ? pa_w[k * 192 + n] : pw_w[(k - 192) * 192 + n];
  if (i < 192) bcat[i] = pa_b[i] + pw_b[i];
}

// ---------------- depthwise 5x5 conv + gelu + residual — sliding-window ----------------
// block = (b, row y, x-half); 384 threads = channels (coalesced 768B/instr).
// Each thread walks 96 x positions keeping the 5x5 tap window in registers:
// 5 fresh loads per output instead of 25, all statically indexed (5-phase unroll).
__global__ __launch_bounds__(384) void dwconv_kernel(const u16* __restrict__ y2,
                                                     const float* __restrict__ dww,
                                                     const float* __restrict__ dwb,
                                                     u16* __restrict__ y2pc) {
  int c = threadIdx.x;
  int blk = blockIdx.x;            // ((b*HH + y)<<1) | half
  int half = blk & 1;
  int row = blk >> 1;
  int y = row % HH;
  int b = row / HH;
  int x0 = half * 96;
  float w[25];
#pragma unroll
  for (int j = 0; j < 25; j++) w[j] = dww[c * 25 + j];
  float bias = dwb[c];
  const u16* rp[5];
  bool rv[5];
#pragma unroll
  for (int dy = 0; dy < 5; dy++) {
    int yy = y + dy - 2;
    rv[dy] = (yy >= 0 && yy < HH);
    rp[dy] = y2 + ((size_t)b * NN + (size_t)(rv[dy] ? yy : y) * WW) * HID + c;
  }
  float win[5][5];
  // preload cols x0-2 .. x0+1 -> slots 3,4,0,1  (slot = (col-x0) mod 5)
#pragma unroll
  for (int j = 0; j < 4; j++) {
    int col = x0 - 2 + j;
    constexpr int slotmap[4] = {3, 4, 0, 1};
    int slot = slotmap[j];
    bool cvld = (col >= 0);            // col < WW always in preload
    int colc = cvld ? col : 0;
#pragma unroll
    for (int dy = 0; dy < 5; dy++) {
      float v = b2f(rp[dy][(size_t)colc * HID]);
      win[dy][slot] = (cvld && rv[dy]) ? v : 0.f;
    }
  }
  u16* op = y2pc + ((size_t)b * NN + (size_t)y * WW) * HID + c;
  for (int tb = 0; tb < 100; tb += 5) {
#pragma unroll
    for (int p = 0; p < 5; p++) {
      int t = tb + p;
      int col = x0 + t + 2;
      const int slot = (p + 2) % 5;          // compile-time
      bool cvld = (col < WW);
      int colc = cvld ? col : (WW - 1);
#pragma unroll
      for (int dy = 0; dy < 5; dy++) {
        float v = b2f(rp[dy][(size_t)colc * HID]);
        win[dy][slot] = (cvld && rv[dy]) ? v : 0.f;
      }
      if (t < 96) {
        float acc = 0.f;
#pragma unroll
        for (int dy = 0; dy < 5; dy++)
#pragma unroll
          for (int dx = 0; dx < 5; dx++)
            acc += w[dy * 5 + dx] * win[dy][(p + 3 + dx) % 5];   // compile-time slot
        float gl = gelu_f(acc + bias);
        float res = win[2][p];               // center tap = y2[y][x][c]
        op[(size_t)(x0 + t) * HID] = f2b(res + gl);
      }
    }
  }
}

// ---------------- td refinement ----------------
__global__ __launch_bounds__(256) void zsum_kernel(const float* __restrict__ sim,
                                                   float* __restrict__ Z) {
  int blk = blockIdx.x;
  int b = blk / NG;
  int n0 = (blk % NG) * 256;
  int tid = threadIdx.x, m = tid & 63, sub = tid >> 6;
  float a = 0.f;
  const float* sp = sim + ((size_t)b * NN + n0) * MM;
  for (int n = sub; n < 256; n += 4) a += __expf(sp[n * MM + m]);
  __shared__ float red[4][64];
  red[sub][m] = a;
  __syncthreads();
  if (tid < 64) atomicAdd(&Z[b * MM + m], red[0][m] + red[1][m] + red[2][m] + red[3][m]);
}

__global__ void invz_kernel(const float* __restrict__ Z, float* __restrict__ invZ) {
  int i = threadIdx.x;  // 128
  invZ[i] = 1.f / Z[i];
}

__global__ __launch_bounds__(192, 2) void tdacc_kernel(const float* __restrict__ sim,
                                                       const float* __restrict__ invZ,
                                                       const u16* __restrict__ ln3x,
                                                       float* __restrict__ tdacc) {
  __shared__ u16 w_s[256][64];  // 32 KB
  int blk = blockIdx.x;
  int b = blk / NG;
  int n0 = (blk % NG) * 256;
  int tid = threadIdx.x;
  const float* sp = sim + ((size_t)b * NN + n0) * MM;
  const float* iz = invZ + b * MM;
  for (int i = tid; i < 256 * 64; i += 192)
    w_s[i >> 6][i & 63] = f2b(__expf(sp[i]) * iz[i & 63]);
  __syncthreads();
  float acc[64];
#pragma unroll
  for (int m = 0; m < 64; m++) acc[m] = 0.f;
  const u16* lp = ln3x + ((size_t)b * NN + n0) * CC + tid;
  for (int n = 0; n < 256; n++) {
    float val = b2f(lp[(size_t)n * CC]);
    const uint4* wr = reinterpret_cast<const uint4*>(&w_s[n][0]);
#pragma unroll
    for (int c8 = 0; c8 < 8; c8++) {
      float f[8]; up8(wr[c8], f);
#pragma unroll
      for (int t = 0; t < 8; t++) acc[c8 * 8 + t] += f[t] * val;
    }
  }
  for (int m = 0; m < 64; m++) atomicAdd(&tdacc[((size_t)b * MM + m) * CC + tid], acc[m]);
}

__global__ void tdfin_kernel(const float* __restrict__ td, const float* __restrict__ sigma,
                             const float* __restrict__ tdacc, float* __restrict__ out) {
  int i = blockIdx.x * 256 + threadIdx.x;  // 24576
  if (i >= BB * MM * CC) return;
  int m = (i / CC) % MM;
  float s = 1.f / (1.f + __expf(-sigma[m]));
  out[i] = s * td[i] + (1.f - s) * tdacc[i];
}

// ---------------- workspace layout (bytes) ----------------
static constexpr size_t oQKV = 0;                                   // u16 BN*576 (later y2 bf16)
static constexpr size_t oXN  = oQKV + (size_t)BN * 576 * 2;         // u16 BN*192 (xn1/xn2/ln3x)
static constexpr size_t oAO  = oXN  + (size_t)BN * CC * 2;          // u16 BN*384 (aca|win; later y2pc)
static constexpr size_t oSIM = oAO  + (size_t)BN * 384 * 2;         // f32 BN*64
static constexpr size_t oQN  = oSIM + (size_t)BN * MM * 4;          // f32 BN*10
static constexpr size_t oRPB = oQN  + (size_t)BN * RC * 4;          // f32 6*65536
static constexpr size_t oVTD = oRPB + (size_t)6 * 65536 * 4;        // f32 BB*MM*CC
static constexpr size_t oKNV = oVTD + (size_t)BB * MM * CC * 4;     // f32 BB*MM*RC
static constexpr size_t oWC  = oKNV + (size_t)BB * MM * RC * 4;     // f32 384*192
static constexpr size_t oBC  = oWC  + (size_t)384 * 192 * 4;        // f32 192 (pad to 1024)
static constexpr size_t oTK  = oBC  + 1024;                         // int BN
static constexpr size_t oSORT= oTK  + (size_t)BN * 4;               // int BN
static constexpr size_t oHIST= oSORT+ (size_t)BN * 4;               // int 128   } contiguous,
static constexpr size_t oBASE= oHIST+ 512;                          // int 128   } zeroed by
static constexpr size_t oZ   = oBASE+ 512;                          // f32 128   } zero_kernel
static constexpr size_t oTDA = oZ   + 512;                          // f32 BB*MM*CC }
static constexpr size_t oINV = oTDA + (size_t)BB * MM * CC * 4;     // f32 128
static constexpr size_t WS_NEEDED = oINV + 512;                     // ~194.4 MB

extern "C" void kernel_launch(void* const* d_in, const int* in_sizes, int n_in,
                              void* d_out, int out_size, void* d_ws, size_t ws_size,
                              hipStream_t stream) {
  if (ws_size < WS_NEEDED) return;  // diagnostic tripwire
  const float* x       = (const float*)d_in[0];
  const float* td      = (const float*)d_in[1];
  const int*   rpi     = (const int*)d_in[2];
  const float* amask   = (const float*)d_in[3];
  const float* n1g     = (const float*)d_in[6];
  const float* n1b     = (const float*)d_in[7];
  const float* n2g     = (const float*)d_in[8];
  const float* n2b     = (const float*)d_in[9];
  const float* n3g     = (const float*)d_in[10];
  const float* n3b     = (const float*)d_in[11];
  const float* wqkv_w  = (const float*)d_in[12];
  const float* wqkv_b  = (const float*)d_in[13];
  const float* wq_w    = (const float*)d_in[14];
  const float* wq_b    = (const float*)d_in[15];
  const float* wk_w    = (const float*)d_in[16];
  const float* wk_b    = (const float*)d_in[17];
  const float* wv_w    = (const float*)d_in[18];
  const float* wv_b    = (const float*)d_in[19];
  const float* atd_sc  = (const float*)d_in[20];
  const float* paca_w  = (const float*)d_in[21];
  const float* paca_b  = (const float*)d_in[22];
  const float* lgsc    = (const float*)d_in[23];
  const float* rpb_tab = (const float*)d_in[24];
  const float* pwin_w  = (const float*)d_in[25];
  const float* pwin_b  = (const float*)d_in[26];
  const float* fc1_w   = (const float*)d_in[27];
  const float* fc1_b   = (const float*)d_in[28];
  const float* dw_w    = (const float*)d_in[29];
  const float* dw_b    = (const float*)d_in[30];
  const float* fc2_w   = (const float*)d_in[31];
  const float* fc2_b   = (const float*)d_in[32];
  const float* sigma   = (const float*)d_in[33];
  float* out = (float*)d_out;
  char* wsb = (char*)d_ws;

  u16*   QKVb = (u16*)(wsb + oQKV);
  u16*   XNb  = (u16*)(wsb + oXN);
  u16*   AOb  = (u16*)(wsb + oAO);
  float* SIM  = (float*)(wsb + oSIM);
  float* QN   = (float*)(wsb + oQN);
  float* RPB  = (float*)(wsb + oRPB);
  float* VTD  = (float*)(wsb + oVTD);
  float* KNV  = (float*)(wsb + oKNV);
  float* WC   = (float*)(wsb + oWC);
  float* BC   = (float*)(wsb + oBC);
  int*   TK   = (int*)(wsb + oTK);
  int*   SORT = (int*)(wsb + oSORT);
  int*   HIST = (int*)(wsb + oHIST);
  int*   BASE = (int*)(wsb + oBASE);
  float* Z    = (float*)(wsb + oZ);
  float* TDA  = (float*)(wsb + oTDA);
  float* INVZ = (float*)(wsb + oINV);

  zero_kernel<<<98, 256, 0, stream>>>(HIST, 24960);  // hist+base+Z+tdacc
  ln1_kernel<<<BN / 4, 256, 0, stream>>>(x, n1g, n1b, wq_w, wq_b, XNb, QN);
  tdproj_kernel<<<BB, 1024, 0, stream>>>(td, wk_w, wk_b, wv_w, wv_b, atd_sc, KNV, VTD);
  gemm_bf<0><<<dim3(BN / 128, 9), 256, 0, stream>>>(XNb, wqkv_w, wqkv_b, QKVb, 192, 576);
  atd_kernel<<<BN / 64, 256, 0, stream>>>(QN, x, KNV, VTD, SIM, TK, out);
  hist_kernel<<<BN / 256, 256, 0, stream>>>(TK, HIST);
  scan_kernel<<<1, 128, 0, stream>>>(HIST, BASE);
  scatter_kernel<<<BB * MM, 256, 0, stream>>>(TK, BASE, SORT);
  rpb_kernel<<<256, 256, 0, stream>>>(rpi, rpb_tab, RPB);
  attn_mfma_kernel<0><<<BB * NG * NHEAD, 256, 0, stream>>>(QKVb, SORT, lgsc, RPB, amask, AOb);
  attn_mfma_kernel<1><<<BB * NG * NHEAD, 256, 0, stream>>>(QKVb, SORT, lgsc, RPB, amask, AOb);
  prep_kernel<<<288, 256, 0, stream>>>(paca_w, pwin_w, paca_b, pwin_b, WC, BC);
  gemm_bf<2><<<dim3(BN / 128, 3), 256, 0, stream>>>(AOb, WC, BC, out, 384, 192);
  ln_kernel<<<BN / 4, 256, 0, stream>>>(out, XNb, n2g, n2b);
  gemm_bf<1><<<dim3(BN / 128, 6), 256, 0, stream>>>(XNb, fc1_w, fc1_b, QKVb, 192, 384);
  dwconv_kernel<<<BB * HH * 2, 384, 0, stream>>>(QKVb, dw_w, dw_b, AOb);
  gemm_bf<2><<<dim3(BN / 128, 3), 256, 0, stream>>>(AOb, fc2_w, fc2_b, out, 384, 192);
  ln_kernel<<<BN / 4, 256, 0, stream>>>(out, XNb, n3g, n3b);
  zsum_kernel<<<BB * NG, 256, 0, stream>>>(SIM, Z);
  invz_kernel<<<1, 128, 0, stream>>>(Z, INVZ);
  tdacc_kernel<<<BB * NG, 192, 0, stream>>>(SIM, INVZ, XNb, TDA);
  tdfin_kernel<<<96, 256, 0, stream>>>(td, sigma, TDA, out + (size_t)BN * CC);
}

// Round 8
// 1285.793 us; speedup vs baseline: 4.7083x; 1.3237x over previous
//
#include <hip/hip_runtime.h>
#include <math.h>

// ---------------- problem constants ----------------
#define BB 2
#define HH 192
#define WW 192
#define NN 36864
#define CC 192
#define NHEAD 6
#define HD 32
#define MM 64
#define RC 10
#define GS 256
#define NG 144
#define HID 384
#define BN 73728

typedef unsigned short u16;
typedef __attribute__((ext_vector_type(8))) short short8;
typedef __attribute__((ext_vector_type(4))) float f32x4;

__device__ __forceinline__ float b2f(u16 u) { return __uint_as_float(((unsigned)u) << 16); }
__device__ __forceinline__ u16 f2b(float f) {
  unsigned v = __float_as_uint(f);
  return (u16)((v + 0x7fffu + ((v >> 16) & 1u)) >> 16);
}
__device__ __forceinline__ void up8(uint4 u, float* f) {
  f[0] = __uint_as_float(u.x << 16); f[1] = __uint_as_float(u.x & 0xffff0000u);
  f[2] = __uint_as_float(u.y << 16); f[3] = __uint_as_float(u.y & 0xffff0000u);
  f[4] = __uint_as_float(u.z << 16); f[5] = __uint_as_float(u.z & 0xffff0000u);
  f[6] = __uint_as_float(u.w << 16); f[7] = __uint_as_float(u.w & 0xffff0000u);
}
__device__ __forceinline__ float gelu_f(float v) {
  return 0.5f * v * (1.f + erff(v * 0.70710678118654752f));
}

// ---------------- zero scratch ----------------
__global__ void zero_kernel(int* __restrict__ p, int n) {
  int i = blockIdx.x * 256 + threadIdx.x;
  if (i < n) p[i] = 0;
}

// ---------------- LN1 fused with ATD q projection (fp32 path) ----------------
__global__ __launch_bounds__(256) void ln1_kernel(const float* __restrict__ x,
                                                  const float* __restrict__ g,
                                                  const float* __restrict__ be,
                                                  const float* __restrict__ wq,
                                                  const float* __restrict__ wqb,
                                                  u16* __restrict__ xnb,
                                                  float* __restrict__ qn) {
  int row = blockIdx.x * 4 + (threadIdx.x >> 6);
  int lane = threadIdx.x & 63;
  const float* p = x + (size_t)row * CC;
  float v0 = p[lane], v1 = p[lane + 64], v2 = p[lane + 128];
  float s = v0 + v1 + v2;
#pragma unroll
  for (int o = 32; o > 0; o >>= 1) s += __shfl_xor(s, o);
  float mu = s * (1.f / 192.f);
  float d0 = v0 - mu, d1 = v1 - mu, d2 = v2 - mu;
  float q2 = d0 * d0 + d1 * d1 + d2 * d2;
#pragma unroll
  for (int o = 32; o > 0; o >>= 1) q2 += __shfl_xor(q2, o);
  float rstd = rsqrtf(q2 * (1.f / 192.f) + 1e-5f);
  float xn0 = d0 * rstd * g[lane] + be[lane];
  float xn1 = d1 * rstd * g[lane + 64] + be[lane + 64];
  float xn2 = d2 * rstd * g[lane + 128] + be[lane + 128];
  u16* op = xnb + (size_t)row * CC;
  op[lane] = f2b(xn0); op[lane + 64] = f2b(xn1); op[lane + 128] = f2b(xn2);
  float qv[RC];
#pragma unroll
  for (int r = 0; r < RC; r++) {
    float t = xn0 * wq[lane * RC + r] + xn1 * wq[(lane + 64) * RC + r] + xn2 * wq[(lane + 128) * RC + r];
#pragma unroll
    for (int o = 32; o > 0; o >>= 1) t += __shfl_xor(t, o);
    qv[r] = t + wqb[r];
  }
  float nr = 0.f;
#pragma unroll
  for (int r = 0; r < RC; r++) nr += qv[r] * qv[r];
  float inv = 1.f / fmaxf(sqrtf(nr), 1e-12f);
  if (lane == 0) {
    float* qo = qn + (size_t)row * RC;
#pragma unroll
    for (int r = 0; r < RC; r++) qo[r] = qv[r] * inv;
  }
}

// ---------------- generic LN -> bf16 out ----------------
__global__ __launch_bounds__(256) void ln_kernel(const float* __restrict__ in,
                                                 u16* __restrict__ out,
                                                 const float* __restrict__ g,
                                                 const float* __restrict__ be) {
  int row = blockIdx.x * 4 + (threadIdx.x >> 6);
  int lane = threadIdx.x & 63;
  const float* p = in + (size_t)row * CC;
  float v0 = p[lane], v1 = p[lane + 64], v2 = p[lane + 128];
  float s = v0 + v1 + v2;
#pragma unroll
  for (int o = 32; o > 0; o >>= 1) s += __shfl_xor(s, o);
  float mu = s * (1.f / 192.f);
  float d0 = v0 - mu, d1 = v1 - mu, d2 = v2 - mu;
  float q2 = d0 * d0 + d1 * d1 + d2 * d2;
#pragma unroll
  for (int o = 32; o > 0; o >>= 1) q2 += __shfl_xor(q2, o);
  float rstd = rsqrtf(q2 * (1.f / 192.f) + 1e-5f);
  u16* op = out + (size_t)row * CC;
  op[lane]       = f2b(d0 * rstd * g[lane] + be[lane]);
  op[lane + 64]  = f2b(d1 * rstd * g[lane + 64] + be[lane + 64]);
  op[lane + 128] = f2b(d2 * rstd * g[lane + 128] + be[lane + 128]);
}

// ---------------- MFMA GEMM: A bf16 [M][K], B f32 [K][Nn] (bf16-converted in staging) ----------------
// 128x64 tile, BK=64, 4 waves (2x2 of 64x32). EPI: 0 = bf16 store ; 1 = gelu+bf16 ; 2 = f32 RMW add
template <int EPI>
__global__ __launch_bounds__(256) void gemm_mfma(const u16* __restrict__ A,
                                                 const float* __restrict__ Bw,
                                                 const float* __restrict__ bias,
                                                 void* __restrict__ Cv,
                                                 int K, int Nn) {
  __shared__ u16 As[128][72];   // 18.4 KB, row stride 144 B (16B-aligned)
  __shared__ u16 Bst[64][72];   // 9.2 KB, transposed [n][k]
  int tid = threadIdx.x;
  int m0 = blockIdx.x * 128, n0 = blockIdx.y * 64;
  int wave = tid >> 6, lane = tid & 63;
  int l16 = lane & 15, l4 = lane >> 4;
  int wm = wave >> 1, wn = wave & 1;
  f32x4 acc[4][2];
#pragma unroll
  for (int mi = 0; mi < 4; mi++)
#pragma unroll
    for (int ni = 0; ni < 2; ni++) acc[mi][ni] = (f32x4){0.f, 0.f, 0.f, 0.f};
  for (int k0 = 0; k0 < K; k0 += 64) {
#pragma unroll
    for (int i = 0; i < 4; i++) {
      int li = tid + i * 256;
      int row = li >> 3, c8 = (li & 7) * 8;
      uint4 v = *reinterpret_cast<const uint4*>(A + (size_t)(m0 + row) * K + k0 + c8);
      *reinterpret_cast<uint4*>(&As[row][c8]) = v;
    }
#pragma unroll
    for (int i = 0; i < 4; i++) {
      int li = tid + i * 256;
      int k = li >> 4, n4 = (li & 15) * 4;
      float4 bv = *reinterpret_cast<const float4*>(Bw + (size_t)(k0 + k) * Nn + n0 + n4);
      Bst[n4 + 0][k] = f2b(bv.x);
      Bst[n4 + 1][k] = f2b(bv.y);
      Bst[n4 + 2][k] = f2b(bv.z);
      Bst[n4 + 3][k] = f2b(bv.w);
    }
    __syncthreads();
#pragma unroll
    for (int kk = 0; kk < 64; kk += 32) {
      short8 af[4], bf[2];
#pragma unroll
      for (int mi = 0; mi < 4; mi++)
        af[mi] = *reinterpret_cast<const short8*>(&As[wm * 64 + mi * 16 + l16][kk + l4 * 8]);
#pragma unroll
      for (int ni = 0; ni < 2; ni++)
        bf[ni] = *reinterpret_cast<const short8*>(&Bst[wn * 32 + ni * 16 + l16][kk + l4 * 8]);
#pragma unroll
      for (int mi = 0; mi < 4; mi++)
#pragma unroll
        for (int ni = 0; ni < 2; ni++)
          acc[mi][ni] = __builtin_amdgcn_mfma_f32_16x16x32_bf16(af[mi], bf[ni], acc[mi][ni], 0, 0, 0);
    }
    __syncthreads();
  }
#pragma unroll
  for (int ni = 0; ni < 2; ni++) {
    int col = n0 + wn * 32 + ni * 16 + l16;
    float bv = bias[col];
#pragma unroll
    for (int mi = 0; mi < 4; mi++) {
#pragma unroll
      for (int r = 0; r < 4; r++) {
        int row = m0 + wm * 64 + mi * 16 + 4 * l4 + r;
        size_t off = (size_t)row * Nn + col;
        float c = acc[mi][ni][r] + bv;
        if constexpr (EPI == 2) {
          ((float*)Cv)[off] += c;
        } else {
          if constexpr (EPI == 1) c = gelu_f(c);
          ((u16*)Cv)[off] = f2b(c);
        }
      }
    }
  }
}

// ---------------- token-dictionary k/v projections (fp32, tiny) ----------------
__global__ __launch_bounds__(1024) void tdproj_kernel(const float* __restrict__ td,
                                                      const float* __restrict__ wk,
                                                      const float* __restrict__ wkb,
                                                      const float* __restrict__ wv,
                                                      const float* __restrict__ wvb,
                                                      const float* __restrict__ atd_scale,
                                                      float* __restrict__ knv,
                                                      float* __restrict__ vtd) {
  int b = blockIdx.x, tid = threadIdx.x;
  __shared__ float td_s[MM * CC];   // 48 KB
  __shared__ float k_s[MM][RC];
  const float* tdb = td + (size_t)b * MM * CC;
  for (int i = tid; i < MM * CC; i += 1024) td_s[i] = tdb[i];
  __syncthreads();
  for (int i = tid; i < MM * CC; i += 1024) {
    int m = i / CC, c = i % CC;
    float a = wvb[c];
    for (int r = 0; r < CC; r++) a += td_s[m * CC + r] * wv[r * CC + c];
    vtd[(size_t)b * MM * CC + i] = a;
  }
  for (int i = tid; i < MM * RC; i += 1024) {
    int m = i / RC, r = i % RC;
    float a = wkb[r];
    for (int c = 0; c < CC; c++) a += td_s[m * CC + c] * wk[c * RC + r];
    k_s[m][r] = a;
  }
  __syncthreads();
  if (tid < MM) {
    int m = tid;
    float nr = 0.f;
    for (int r = 0; r < RC; r++) nr += k_s[m][r] * k_s[m][r];
    float inv = 1.f / fmaxf(sqrtf(nr), 1e-12f);
    float sc = 1.f + fminf(fmaxf(atd_scale[m], 0.f), 1.f) * 4.1588830833596715f; // ln(64)
    for (int r = 0; r < RC; r++) knv[(size_t)b * MM * RC + m * RC + r] = k_s[m][r] * inv * sc;
  }
}

// ---------------- ATD cross attention (fp32): sim, tk_id, xacc = x + x_atd ----------------
__global__ __launch_bounds__(256, 2) void atd_kernel(const float* __restrict__ qn,
                                                     const float* __restrict__ x,
                                                     const float* __restrict__ knv,
                                                     const float* __restrict__ vtd,
                                                     float* __restrict__ sim,
                                                     int* __restrict__ tkid,
                                                     float* __restrict__ xacc) {
  __shared__ float v_s[MM][CC];   // 48 KB
  __shared__ float kn_s[MM][11];
  __shared__ float p_s[4][64];
  int tid = threadIdx.x;
  int b = (blockIdx.x * 64) / NN;
  float* vflat = &v_s[0][0];
  for (int i = tid; i < MM * CC; i += 256) vflat[i] = vtd[(size_t)b * MM * CC + i];
  for (int i = tid; i < MM * RC; i += 256) kn_s[i / RC][i % RC] = knv[(size_t)b * MM * RC + i];
  __syncthreads();
  int wave = tid >> 6, lane = tid & 63;
  for (int it = 0; it < 16; it++) {
    int tg = blockIdx.x * 64 + it * 4 + wave;
    const float* qr = qn + (size_t)tg * RC;
    float s = 0.f;
#pragma unroll
    for (int r = 0; r < RC; r++) s += qr[r] * kn_s[lane][r];
    float mx = s; int ai = lane;
#pragma unroll
    for (int o = 32; o > 0; o >>= 1) {
      float ov = __shfl_xor(mx, o); int oi = __shfl_xor(ai, o);
      if (ov > mx || (ov == mx && oi < ai)) { mx = ov; ai = oi; }
    }
    float e = __expf(s - mx);
    float sum = e;
#pragma unroll
    for (int o = 32; o > 0; o >>= 1) sum += __shfl_xor(sum, o);
    float p = e / sum;
    sim[(size_t)tg * MM + lane] = p;
    if (lane == 0) tkid[tg] = ai;
    p_s[wave][lane] = p;
    float a0 = 0.f, a1 = 0.f, a2 = 0.f;
#pragma unroll
    for (int m = 0; m < MM; m++) {
      float pm = p_s[wave][m];
      a0 += pm * v_s[m][lane];
      a1 += pm * v_s[m][lane + 64];
      a2 += pm * v_s[m][lane + 128];
    }
    const float* xr = x + (size_t)tg * CC;
    float* xo = xacc + (size_t)tg * CC;
    xo[lane]       = xr[lane]       + a0;
    xo[lane + 64]  = xr[lane + 64]  + a1;
    xo[lane + 128] = xr[lane + 128] + a2;
  }
}

// ---------------- stable counting sort of tk_id ----------------
__global__ void hist_kernel(const int* __restrict__ tkid, int* __restrict__ hist) {
  int i = blockIdx.x * 256 + threadIdx.x;
  if (i < BN) atomicAdd(&hist[(i / NN) * MM + tkid[i]], 1);
}

__global__ void scan_kernel(const int* __restrict__ hist, int* __restrict__ base) {
  int lane = threadIdx.x & 63, b = threadIdx.x >> 6;  // 128 threads
  int v = hist[b * MM + lane];
  int xx = v;
#pragma unroll
  for (int o = 1; o < 64; o <<= 1) { int t = __shfl_up(xx, o); if (lane >= o) xx += t; }
  base[b * MM + lane] = xx - v;
}

__global__ __launch_bounds__(256) void scatter_kernel(const int* __restrict__ tkid,
                                                      const int* __restrict__ base,
                                                      int* __restrict__ sort_idx) {
  int bk = blockIdx.x;
  int b = bk >> 6, key = bk & 63;
  int tid = threadIdx.x, wave = tid >> 6, lane = tid & 63;
  __shared__ int wtot[4];
  int offset = base[b * MM + key];
  const int* tk = tkid + (size_t)b * NN;
  for (int c0 = 0; c0 < NN; c0 += 256) {
    int i = c0 + tid;
    bool f = (tk[i] == key);
    unsigned long long mb = __ballot(f);
    int wpre = __popcll(mb & ((1ull << lane) - 1ull));
    if (lane == 0) wtot[wave] = __popcll(mb);
    __syncthreads();
    int pre = wpre;
#pragma unroll
    for (int w = 0; w < 4; w++) if (w < wave) pre += wtot[w];
    int tot = wtot[0] + wtot[1] + wtot[2] + wtot[3];
    if (f) sort_idx[(size_t)b * NN + offset + pre] = i;
    offset += tot;
    __syncthreads();
  }
}

// ---------------- rpb gather: TRANSPOSED [h][k][q] so C-in loads are float4 ----------------
__global__ void rpb_kernel(const int* __restrict__ rpi, const float* __restrict__ table,
                           float* __restrict__ rpbT) {
  int ij = blockIdx.x * 256 + threadIdx.x;  // 65536 = q*256 + k
  int q = ij >> 8, k = ij & 255;
  int idx = rpi[ij];
#pragma unroll
  for (int h = 0; h < NHEAD; h++) rpbT[h * 65536 + k * 256 + q] = table[idx * NHEAD + h];
}

// ---------------- MFMA attention, merged modes, full-S softmax ----------------
// mode 0 = acmsa (first 1728 blocks), mode 1 = winmsa (rpb C-in + boundary mask).
// Per qt-tile: 16 QK MFMAs -> full-row softmax (pre-normalized P) -> 16 PV MFMAs.
__global__ __launch_bounds__(256, 3) void attn_mfma_kernel(const u16* __restrict__ qkv,
                                                           const int* __restrict__ sort_idx,
                                                           const float* __restrict__ lgsc,
                                                           const float* __restrict__ rpbT,
                                                           const float* __restrict__ amask,
                                                           u16* __restrict__ ao) {
  __shared__ u16 Ks[GS][40];       // 20.5 KB
  __shared__ u16 Vt[HD][GS + 8];   // 16.9 KB, transposed
  __shared__ u16 Ps[4][16][72];    // 9.2 KB, per-wave per-qt P chunk
  int idx = blockIdx.x;
  int mode = 0;
  if (idx >= BB * NG * NHEAD) { mode = 1; idx -= BB * NG * NHEAD; }
  int h = idx % NHEAD; idx /= NHEAD;
  int g = idx % NG;    idx /= NG;
  int b = idx;
  int tid = threadIdx.x;
  int wave = tid >> 6, lane = tid & 63;
  int l16 = lane & 15, l4 = lane >> 4;
  const int* sp = sort_idx + (size_t)b * NN + g * GS;
  int wy = g / 12, wx = g % 12;

  auto tokof = [&](int i) -> int {
    if (mode == 0) return sp[i];
    int sy = (wy * 16 + (i >> 4) + 8) % 192;
    int sx = (wx * 16 + (i & 15) + 8) % 192;
    return sy * 192 + sx;
  };

  // ---- stage K ([tok][ch]) and V transposed ([ch][tok]) ----
#pragma unroll
  for (int it = 0; it < 4; it++) {
    int li = tid + it * 256;             // 0..1023
    int tok = li >> 2, q8 = (li & 3) * 8;
    size_t bas = ((size_t)b * NN + tokof(tok)) * 576 + h * HD + q8;
    uint4 kv = *reinterpret_cast<const uint4*>(qkv + bas + CC);
    *reinterpret_cast<uint4*>(&Ks[tok][q8]) = kv;
    ushort4 v0 = *reinterpret_cast<const ushort4*>(qkv + bas + 2 * CC);
    ushort4 v1 = *reinterpret_cast<const ushort4*>(qkv + bas + 2 * CC + 4);
    Vt[q8 + 0][tok] = v0.x; Vt[q8 + 1][tok] = v0.y;
    Vt[q8 + 2][tok] = v0.z; Vt[q8 + 3][tok] = v0.w;
    Vt[q8 + 4][tok] = v1.x; Vt[q8 + 5][tok] = v1.y;
    Vt[q8 + 6][tok] = v1.z; Vt[q8 + 7][tok] = v1.w;
  }
  float qscale = (mode == 0) ? __expf(fminf(lgsc[0], 4.605170185988092f))
                             : 0.17677669529663687f;
  bool bnd = (mode == 1) && ((wy == 11) || (wx == 11));
  __syncthreads();

  for (int qt = 0; qt < 4; qt++) {
    // ---- Q fragment (scale folded) ----
    int q0 = wave * 64 + qt * 16 + 4 * l4;
    short8 qf;
    {
      int qrow = wave * 64 + qt * 16 + l16;
      size_t bas = ((size_t)b * NN + tokof(qrow)) * 576 + h * HD + l4 * 8;
      uint4 u = *reinterpret_cast<const uint4*>(qkv + bas);
      float f[8]; up8(u, f);
#pragma unroll
      for (int j = 0; j < 8; j++) ((u16*)&qf)[j] = f2b(f[j] * qscale);
    }
    // ---- S = Q·K^T (+ rpb as C-in for mode 1) ----
    f32x4 S[16];
#pragma unroll
    for (int kt = 0; kt < 16; kt++) {
      short8 kf = *reinterpret_cast<const short8*>(&Ks[kt * 16 + l16][l4 * 8]);
      f32x4 cin = (f32x4){0.f, 0.f, 0.f, 0.f};
      if (mode == 1)
        cin = *reinterpret_cast<const f32x4*>(rpbT + h * 65536 + (kt * 16 + l16) * 256 + q0);
      S[kt] = __builtin_amdgcn_mfma_f32_16x16x32_bf16(qf, kf, cin, 0, 0, 0);
    }
    if (bnd) {
#pragma unroll
      for (int kt = 0; kt < 16; kt++)
#pragma unroll
        for (int r = 0; r < 4; r++)
          S[kt][r] += amask[(size_t)g * 65536 + (size_t)(q0 + r) * 256 + kt * 16 + l16];
    }
    // ---- full-row softmax, P pre-normalized ----
#pragma unroll
    for (int r = 0; r < 4; r++) {
      float m = S[0][r];
#pragma unroll
      for (int kt = 1; kt < 16; kt++) m = fmaxf(m, S[kt][r]);
#pragma unroll
      for (int o = 1; o < 16; o <<= 1) m = fmaxf(m, __shfl_xor(m, o));
      float sum = 0.f;
#pragma unroll
      for (int kt = 0; kt < 16; kt++) {
        float p = __expf(S[kt][r] - m);
        S[kt][r] = p;
        sum += p;
      }
#pragma unroll
      for (int o = 1; o < 16; o <<= 1) sum += __shfl_xor(sum, o);
      float inv = 1.f / sum;
#pragma unroll
      for (int kt = 0; kt < 16; kt++) S[kt][r] *= inv;
    }
    // ---- O = P·V, chunked by 64 keys (wave-private Ps, no barrier) ----
    f32x4 O0 = (f32x4){0.f, 0.f, 0.f, 0.f};
    f32x4 O1 = (f32x4){0.f, 0.f, 0.f, 0.f};
    for (int kc = 0; kc < 4; kc++) {
#pragma unroll
      for (int kt = 0; kt < 4; kt++)
#pragma unroll
        for (int r = 0; r < 4; r++)
          Ps[wave][4 * l4 + r][kt * 16 + l16] = f2b(S[kc * 4 + kt][r]);
#pragma unroll
      for (int s = 0; s < 2; s++) {
        short8 pa = *reinterpret_cast<const short8*>(&Ps[wave][l16][s * 32 + l4 * 8]);
        short8 v0 = *reinterpret_cast<const short8*>(&Vt[l16][kc * 64 + s * 32 + l4 * 8]);
        short8 v1 = *reinterpret_cast<const short8*>(&Vt[16 + l16][kc * 64 + s * 32 + l4 * 8]);
        O0 = __builtin_amdgcn_mfma_f32_16x16x32_bf16(pa, v0, O0, 0, 0, 0);
        O1 = __builtin_amdgcn_mfma_f32_16x16x32_bf16(pa, v1, O1, 0, 0, 0);
      }
    }
    // ---- store (P already normalized) ----
    int coff = mode ? CC : 0;
#pragma unroll
    for (int r = 0; r < 4; r++) {
      int tok = tokof(q0 + r);
      u16* ob = ao + ((size_t)b * NN + tok) * 384 + coff + h * HD;
      ob[l16]      = f2b(O0[r]);
      ob[16 + l16] = f2b(O1[r]);
    }
  }
}

// ---------------- concat proj weights / biases ----------------
__global__ void prep_kernel(const float* __restrict__ pa_w, const float* __restrict__ pw_w,
                            const float* __restrict__ pa_b, const float* __restrict__ pw_b,
                            float* __restrict__ wcat, float* __restrict__ bcat) {
  int i = blockIdx.x * 256 + threadIdx.x;  // 73728
  int k = i / 192, n = i % 192;
  wcat[i] = (k < 192) ? pa_w[k * 192 + n] : pw_w[(k - 192) * 192 + n];
  if (i < 192) bcat[i] = pa_b[i] + pw_b[i];
}

// ---------------- depthwise 5x5 conv + gelu + residual — sliding-window ----------------
__global__ __launch_bounds__(384) void dwconv_kernel(const u16* __restrict__ y2,
                                                     const float* __restrict__ dww,
                                                     const float* __restrict__ dwb,
                                                     u16* __restrict__ y2pc) {
  int c = threadIdx.x;
  int blk = blockIdx.x;            // ((b*HH + y)<<1) | half
  int half = blk & 1;
  int row = blk >> 1;
  int y = row % HH;
  int b = row / HH;
  int x0 = half * 96;
  float w[25];
#pragma unroll
  for (int j = 0; j < 25; j++) w[j] = dww[c * 25 + j];
  float bias = dwb[c];
  const u16* rp[5];
  bool rv[5];
#pragma unroll
  for (int dy = 0; dy < 5; dy++) {
    int yy = y + dy - 2;
    rv[dy] = (yy >= 0 && yy < HH);
    rp[dy] = y2 + ((size_t)b * NN + (size_t)(rv[dy] ? yy : y) * WW) * HID + c;
  }
  float win[5][5];
#pragma unroll
  for (int j = 0; j < 4; j++) {
    int col = x0 - 2 + j;
    constexpr int slotmap[4] = {3, 4, 0, 1};
    int slot = slotmap[j];
    bool cvld = (col >= 0);
    int colc = cvld ? col : 0;
#pragma unroll
    for (int dy = 0; dy < 5; dy++) {
      float v = b2f(rp[dy][(size_t)colc * HID]);
      win[dy][slot] = (cvld && rv[dy]) ? v : 0.f;
    }
  }
  u16* op = y2pc + ((size_t)b * NN + (size_t)y * WW) * HID + c;
  for (int tb = 0; tb < 100; tb += 5) {
#pragma unroll
    for (int p = 0; p < 5; p++) {
      int t = tb + p;
      int col = x0 + t + 2;
      const int slot = (p + 2) % 5;
      bool cvld = (col < WW);
      int colc = cvld ? col : (WW - 1);
#pragma unroll
      for (int dy = 0; dy < 5; dy++) {
        float v = b2f(rp[dy][(size_t)colc * HID]);
        win[dy][slot] = (cvld && rv[dy]) ? v : 0.f;
      }
      if (t < 96) {
        float acc = 0.f;
#pragma unroll
        for (int dy = 0; dy < 5; dy++)
#pragma unroll
          for (int dx = 0; dx < 5; dx++)
            acc += w[dy * 5 + dx] * win[dy][(p + 3 + dx) % 5];
        float gl = gelu_f(acc + bias);
        float res = win[2][p];
        op[(size_t)(x0 + t) * HID] = f2b(res + gl);
      }
    }
  }
}

// ---------------- td refinement ----------------
__global__ __launch_bounds__(256) void zsum_kernel(const float* __restrict__ sim,
                                                   float* __restrict__ Z) {
  int blk = blockIdx.x;
  int b = blk / NG;
  int n0 = (blk % NG) * 256;
  int tid = threadIdx.x, m = tid & 63, sub = tid >> 6;
  float a = 0.f;
  const float* sp = sim + ((size_t)b * NN + n0) * MM;
  for (int n = sub; n < 256; n += 4) a += __expf(sp[n * MM + m]);
  __shared__ float red[4][64];
  red[sub][m] = a;
  __syncthreads();
  if (tid < 64) atomicAdd(&Z[b * MM + m], red[0][m] + red[1][m] + red[2][m] + red[3][m]);
}

__global__ void invz_kernel(const float* __restrict__ Z, float* __restrict__ invZ) {
  int i = threadIdx.x;  // 128
  invZ[i] = 1.f / Z[i];
}

__global__ __launch_bounds__(192, 2) void tdacc_kernel(const float* __restrict__ sim,
                                                       const float* __restrict__ invZ,
                                                       const u16* __restrict__ ln3x,
                                                       float* __restrict__ tdacc) {
  __shared__ u16 w_s[256][64];  // 32 KB
  int blk = blockIdx.x;
  int b = blk / NG;
  int n0 = (blk % NG) * 256;
  int tid = threadIdx.x;
  const float* sp = sim + ((size_t)b * NN + n0) * MM;
  const float* iz = invZ + b * MM;
  for (int i = tid; i < 256 * 64; i += 192)
    w_s[i >> 6][i & 63] = f2b(__expf(sp[i]) * iz[i & 63]);
  __syncthreads();
  float acc[64];
#pragma unroll
  for (int m = 0; m < 64; m++) acc[m] = 0.f;
  const u16* lp = ln3x + ((size_t)b * NN + n0) * CC + tid;
  for (int n = 0; n < 256; n++) {
    float val = b2f(lp[(size_t)n * CC]);
    const uint4* wr = reinterpret_cast<const uint4*>(&w_s[n][0]);
#pragma unroll
    for (int c8 = 0; c8 < 8; c8++) {
      float f[8]; up8(wr[c8], f);
#pragma unroll
      for (int t = 0; t < 8; t++) acc[c8 * 8 + t] += f[t] * val;
    }
  }
  for (int m = 0; m < 64; m++) atomicAdd(&tdacc[((size_t)b * MM + m) * CC + tid], acc[m]);
}

__global__ void tdfin_kernel(const float* __restrict__ td, const float* __restrict__ sigma,
                             const float* __restrict__ tdacc, float* __restrict__ out) {
  int i = blockIdx.x * 256 + threadIdx.x;  // 24576
  if (i >= BB * MM * CC) return;
  int m = (i / CC) % MM;
  float s = 1.f / (1.f + __expf(-sigma[m]));
  out[i] = s * td[i] + (1.f - s) * tdacc[i];
}

// ---------------- workspace layout (bytes) ----------------
static constexpr size_t oQKV = 0;                                   // u16 BN*576 (later y2 bf16)
static constexpr size_t oXN  = oQKV + (size_t)BN * 576 * 2;         // u16 BN*192 (xn1/xn2/ln3x)
static constexpr size_t oAO  = oXN  + (size_t)BN * CC * 2;          // u16 BN*384 (aca|win; later y2pc)
static constexpr size_t oSIM = oAO  + (size_t)BN * 384 * 2;         // f32 BN*64
static constexpr size_t oQN  = oSIM + (size_t)BN * MM * 4;          // f32 BN*10
static constexpr size_t oRPB = oQN  + (size_t)BN * RC * 4;          // f32 6*65536 (transposed [h][k][q])
static constexpr size_t oVTD = oRPB + (size_t)6 * 65536 * 4;        // f32 BB*MM*CC
static constexpr size_t oKNV = oVTD + (size_t)BB * MM * CC * 4;     // f32 BB*MM*RC
static constexpr size_t oWC  = oKNV + (size_t)BB * MM * RC * 4;     // f32 384*192
static constexpr size_t oBC  = oWC  + (size_t)384 * 192 * 4;        // f32 192 (pad to 1024)
static constexpr size_t oTK  = oBC  + 1024;                         // int BN
static constexpr size_t oSORT= oTK  + (size_t)BN * 4;               // int BN
static constexpr size_t oHIST= oSORT+ (size_t)BN * 4;               // int 128   } contiguous,
static constexpr size_t oBASE= oHIST+ 512;                          // int 128   } zeroed by
static constexpr size_t oZ   = oBASE+ 512;                          // f32 128   } zero_kernel
static constexpr size_t oTDA = oZ   + 512;                          // f32 BB*MM*CC }
static constexpr size_t oINV = oTDA + (size_t)BB * MM * CC * 4;     // f32 128
static constexpr size_t WS_NEEDED = oINV + 512;                     // ~194.4 MB

extern "C" void kernel_launch(void* const* d_in, const int* in_sizes, int n_in,
                              void* d_out, int out_size, void* d_ws, size_t ws_size,
                              hipStream_t stream) {
  if (ws_size < WS_NEEDED) return;  // diagnostic tripwire
  const float* x       = (const float*)d_in[0];
  const float* td      = (const float*)d_in[1];
  const int*   rpi     = (const int*)d_in[2];
  const float* amask   = (const float*)d_in[3];
  const float* n1g     = (const float*)d_in[6];
  const float* n1b     = (const float*)d_in[7];
  const float* n2g     = (const float*)d_in[8];
  const float* n2b     = (const float*)d_in[9];
  const float* n3g     = (const float*)d_in[10];
  const float* n3b     = (const float*)d_in[11];
  const float* wqkv_w  = (const float*)d_in[12];
  const float* wqkv_b  = (const float*)d_in[13];
  const float* wq_w    = (const float*)d_in[14];
  const float* wq_b    = (const float*)d_in[15];
  const float* wk_w    = (const float*)d_in[16];
  const float* wk_b    = (const float*)d_in[17];
  const float* wv_w    = (const float*)d_in[18];
  const float* wv_b    = (const float*)d_in[19];
  const float* atd_sc  = (const float*)d_in[20];
  const float* paca_w  = (const float*)d_in[21];
  const float* paca_b  = (const float*)d_in[22];
  const float* lgsc    = (const float*)d_in[23];
  const float* rpb_tab = (const float*)d_in[24];
  const float* pwin_w  = (const float*)d_in[25];
  const float* pwin_b  = (const float*)d_in[26];
  const float* fc1_w   = (const float*)d_in[27];
  const float* fc1_b   = (const float*)d_in[28];
  const float* dw_w    = (const float*)d_in[29];
  const float* dw_b    = (const float*)d_in[30];
  const float* fc2_w   = (const float*)d_in[31];
  const float* fc2_b   = (const float*)d_in[32];
  const float* sigma   = (const float*)d_in[33];
  float* out = (float*)d_out;
  char* wsb = (char*)d_ws;

  u16*   QKVb = (u16*)(wsb + oQKV);
  u16*   XNb  = (u16*)(wsb + oXN);
  u16*   AOb  = (u16*)(wsb + oAO);
  float* SIM  = (float*)(wsb + oSIM);
  float* QN   = (float*)(wsb + oQN);
  float* RPB  = (float*)(wsb + oRPB);
  float* VTD  = (float*)(wsb + oVTD);
  float* KNV  = (float*)(wsb + oKNV);
  float* WC   = (float*)(wsb + oWC);
  float* BC   = (float*)(wsb + oBC);
  int*   TK   = (int*)(wsb + oTK);
  int*   SORT = (int*)(wsb + oSORT);
  int*   HIST = (int*)(wsb + oHIST);
  int*   BASE = (int*)(wsb + oBASE);
  float* Z    = (float*)(wsb + oZ);
  float* TDA  = (float*)(wsb + oTDA);
  float* INVZ = (float*)(wsb + oINV);

  zero_kernel<<<98, 256, 0, stream>>>(HIST, 24960);  // hist+base+Z+tdacc
  ln1_kernel<<<BN / 4, 256, 0, stream>>>(x, n1g, n1b, wq_w, wq_b, XNb, QN);
  tdproj_kernel<<<BB, 1024, 0, stream>>>(td, wk_w, wk_b, wv_w, wv_b, atd_sc, KNV, VTD);
  gemm_mfma<0><<<dim3(BN / 128, 9), 256, 0, stream>>>(XNb, wqkv_w, wqkv_b, QKVb, 192, 576);
  atd_kernel<<<BN / 64, 256, 0, stream>>>(QN, x, KNV, VTD, SIM, TK, out);
  hist_kernel<<<BN / 256, 256, 0, stream>>>(TK, HIST);
  scan_kernel<<<1, 128, 0, stream>>>(HIST, BASE);
  scatter_kernel<<<BB * MM, 256, 0, stream>>>(TK, BASE, SORT);
  rpb_kernel<<<256, 256, 0, stream>>>(rpi, rpb_tab, RPB);
  attn_mfma_kernel<<<2 * BB * NG * NHEAD, 256, 0, stream>>>(QKVb, SORT, lgsc, RPB, amask, AOb);
  prep_kernel<<<288, 256, 0, stream>>>(paca_w, pwin_w, paca_b, pwin_b, WC, BC);
  gemm_mfma<2><<<dim3(BN / 128, 3), 256, 0, stream>>>(AOb, WC, BC, out, 384, 192);
  ln_kernel<<<BN / 4, 256, 0, stream>>>(out, XNb, n2g, n2b);
  gemm_mfma<1><<<dim3(BN / 128, 6), 256, 0, stream>>>(XNb, fc1_w, fc1_b, QKVb, 192, 384);
  dwconv_kernel<<<BB * HH * 2, 384, 0, stream>>>(QKVb, dw_w, dw_b, AOb);
  gemm_mfma<2><<<dim3(BN / 128, 3), 256, 0, stream>>>(AOb, fc2_w, fc2_b, out, 384, 192);
  ln_kernel<<<BN / 4, 256, 0, stream>>>(out, XNb, n3g, n3b);
  zsum_kernel<<<BB * NG, 256, 0, stream>>>(SIM, Z);
  invz_kernel<<<1, 128, 0, stream>>>(Z, INVZ);
  tdacc_kernel<<<BB * NG, 192, 0, stream>>>(SIM, INVZ, XNb, TDA);
  tdfin_kernel<<<96, 256, 0, stream>>>(td, sigma, TDA, out + (size_t)BN * CC);
}